// Round 1
// baseline (807.423 us; speedup 1.0000x reference)
//
#include <hip/hip_runtime.h>
#include <math.h>

// HyperbolicMultiHeadAttention — round 0: correct fp32 baseline.
// B=2, S=1024, D=1024, H=16, dh=64. All fp32.
// Pipeline:
//   1) gemm_nt (z=3): qt/kt/vt = x @ W{q,k,v}^T           [2048,1024] each
//   2) hyper_maps:    q_h,k_h = exp_map;  v_tan = log(exp(v)); qns,kns
//   3) attn (flash):  per (b,h,qtile64) online-softmax over hyperbolic
//                     distance scores; epilogue exp_map+log_map -> concat
//   4) gemm_nt (z=1): out = concat @ W_o^T
// ws layout (floats): qt[2M] kt[2M] vt[2M] concat[2M] qns[32K] kns[32K] ~33.8MB

#define EPS_ 1e-5f

constexpr int Bb = 2, Ss = 1024, Dd = 1024, Hh = 16, DHh = 64;

__device__ __forceinline__ float softplusf_(float x) {
    return (x > 20.f) ? x : log1pf(expf(x));
}

__device__ __forceinline__ float waveSum64(float v) {
#pragma unroll
    for (int m = 32; m >= 1; m >>= 1) v += __shfl_xor(v, m, 64);
    return v;
}

// C[M,N] = A[M,K] @ B[N,K]^T, all row-major. 128x128 tile, BK=8, 8x8/thread.
// blockIdx.z selects (B,C) pair so QKV runs in one dispatch.
__global__ __launch_bounds__(256) void gemm_nt(
    const float* __restrict__ A,
    const float* __restrict__ B0, const float* __restrict__ B1, const float* __restrict__ B2,
    float* __restrict__ C0, float* __restrict__ C1, float* __restrict__ C2,
    int M, int N, int K)
{
    const float* Bp = (blockIdx.z == 0) ? B0 : (blockIdx.z == 1 ? B1 : B2);
    float* Cp = (blockIdx.z == 0) ? C0 : (blockIdx.z == 1 ? C1 : C2);
    __shared__ float As[8][128];
    __shared__ float Bs[8][128];
    const int tid = threadIdx.x;
    const int tx = tid & 15, ty = tid >> 4;
    const int bm = blockIdx.y * 128, bn = blockIdx.x * 128;
    const int lr = tid >> 1, lc = (tid & 1) << 2;  // 128 rows x 8 k, float4/thread
    float acc[8][8] = {};
    for (int k0 = 0; k0 < K; k0 += 8) {
        float4 a4 = *(const float4*)(A  + (size_t)(bm + lr) * K + k0 + lc);
        float4 b4 = *(const float4*)(Bp + (size_t)(bn + lr) * K + k0 + lc);
        __syncthreads();
        As[lc + 0][lr] = a4.x; As[lc + 1][lr] = a4.y; As[lc + 2][lr] = a4.z; As[lc + 3][lr] = a4.w;
        Bs[lc + 0][lr] = b4.x; Bs[lc + 1][lr] = b4.y; Bs[lc + 2][lr] = b4.z; Bs[lc + 3][lr] = b4.w;
        __syncthreads();
#pragma unroll
        for (int k = 0; k < 8; ++k) {
            float av[8], bv[8];
#pragma unroll
            for (int i = 0; i < 8; i++) av[i] = As[k][ty * 8 + i];
#pragma unroll
            for (int j = 0; j < 8; j++) bv[j] = Bs[k][tx * 8 + j];
#pragma unroll
            for (int i = 0; i < 8; i++)
#pragma unroll
                for (int j = 0; j < 8; j++)
                    acc[i][j] = fmaf(av[i], bv[j], acc[i][j]);
        }
    }
#pragma unroll
    for (int i = 0; i < 8; i++) {
        float4 o0 = make_float4(acc[i][0], acc[i][1], acc[i][2], acc[i][3]);
        float4 o1 = make_float4(acc[i][4], acc[i][5], acc[i][6], acc[i][7]);
        float* cr = Cp + (size_t)(bm + ty * 8 + i) * N + bn + tx * 8;
        *(float4*)cr = o0;
        *(float4*)(cr + 4) = o1;
    }
}

// One wave per (row, head) vector of 64. blockIdx.y: 0=q, 1=k, 2=v.
// q,k: y = exp_map(x); store y and ||y||^2. v: y = log_map(exp_map(x)).
// In-place safe (each lane owns its element).
__global__ __launch_bounds__(256) void hyper_maps(
    const float* __restrict__ qt, const float* __restrict__ kt, const float* __restrict__ vt,
    float* __restrict__ qh, float* __restrict__ kh, float* __restrict__ vtan,
    float* __restrict__ qns, float* __restrict__ kns,
    const float* __restrict__ p_logc)
{
    const float c = softplusf_(p_logc[0]);
    const float sc = sqrtf(c);
    const int which = blockIdx.y;
    const int wv = threadIdx.x >> 6, lane = threadIdx.x & 63;
    const int vec = blockIdx.x * 4 + wv;            // 0..32767
    const int row = vec >> 4, h = vec & 15;
    const size_t off = (size_t)row * Dd + h * DHh + lane;

    const float* src = (which == 0) ? qt : (which == 1) ? kt : vt;
    float x = src[off];
    float ns = waveSum64(x * x);
    float n = fmaxf(sqrtf(ns), EPS_);
    float th = tanhf(sc * n);
    float y = x * (th / (sc * n));                  // exp_map_at_origin

    if (which == 0) {
        qh[off] = y;
        float yns = waveSum64(y * y);
        if (lane == 0) qns[vec] = yns;
    } else if (which == 1) {
        kh[off] = y;
        float yns = waveSum64(y * y);
        if (lane == 0) kns[vec] = yns;
    } else {
        // log_map_at_origin(y) — numerically, matching reference fp32 path
        float yn2 = waveSum64(y * y);
        float yn = fmaxf(sqrtf(yn2), EPS_);
        float ycl = fminf(yn, 1.f / sc - EPS_);
        float fac = atanhf(sc * ycl) / (sc * yn);
        vtan[off] = y * fac;
    }
}

// Flash-style attention per (b,h,64-query tile). 256 threads = 16x16,
// 4x4 micro-tile per thread. P reuses the K LDS buffer (KPs).
__global__ __launch_bounds__(256) void attn(
    const float* __restrict__ qh, const float* __restrict__ kh, const float* __restrict__ vtan,
    const float* __restrict__ qns, const float* __restrict__ kns,
    float* __restrict__ concat,
    const float* __restrict__ p_logc, const float* __restrict__ p_beta,
    const float* __restrict__ p_bias)
{
    const float c = softplusf_(p_logc[0]);
    const float sc = sqrtf(c);
    const float bp = softplusf_(p_beta[0]);
    const float ab = p_bias[0];

    const int h = blockIdx.y, b = blockIdx.z, q0 = blockIdx.x * 64;
    __shared__ float Qs[64][65];
    __shared__ float KPs[64][65];   // K chunk, then reused for P
    __shared__ float Vs[64][65];
    __shared__ float Qn[64];
    __shared__ float Kn[64];

    const int tid = threadIdx.x;
    const int tx = tid & 15, ty = tid >> 4;
    const int r0 = ty * 4, c0 = tx * 4;

    {   // load Q tile [64 rows][64 dh]
        int r = tid >> 2, cb = (tid & 3) << 4;
        const float* src = qh + (size_t)(b * Ss + q0 + r) * Dd + h * DHh + cb;
#pragma unroll
        for (int u = 0; u < 16; u += 4) {
            float4 v4 = *(const float4*)(src + u);
            Qs[r][cb + u + 0] = v4.x; Qs[r][cb + u + 1] = v4.y;
            Qs[r][cb + u + 2] = v4.z; Qs[r][cb + u + 3] = v4.w;
        }
    }
    if (tid < 64) Qn[tid] = qns[(size_t)(b * Ss + q0 + tid) * Hh + h];

    float m_i[4], l_i[4], O[4][4];
#pragma unroll
    for (int i = 0; i < 4; i++) {
        m_i[i] = -1e30f; l_i[i] = 0.f;
#pragma unroll
        for (int j = 0; j < 4; j++) O[i][j] = 0.f;
    }

    for (int kt0 = 0; kt0 < Ss; kt0 += 64) {
        __syncthreads();   // previous PV done reading KPs/Vs
        {   // load K and V chunk
            int r = tid >> 2, cb = (tid & 3) << 4;
            const float* ksrc = kh   + (size_t)(b * Ss + kt0 + r) * Dd + h * DHh + cb;
            const float* vsrc = vtan + (size_t)(b * Ss + kt0 + r) * Dd + h * DHh + cb;
#pragma unroll
            for (int u = 0; u < 16; u += 4) {
                float4 kv = *(const float4*)(ksrc + u);
                KPs[r][cb + u + 0] = kv.x; KPs[r][cb + u + 1] = kv.y;
                KPs[r][cb + u + 2] = kv.z; KPs[r][cb + u + 3] = kv.w;
                float4 vv = *(const float4*)(vsrc + u);
                Vs[r][cb + u + 0] = vv.x; Vs[r][cb + u + 1] = vv.y;
                Vs[r][cb + u + 2] = vv.z; Vs[r][cb + u + 3] = vv.w;
            }
        }
        if (tid < 64) Kn[tid] = kns[(size_t)(b * Ss + kt0 + tid) * Hh + h];
        __syncthreads();

        // scores: 4x4 dot over dh=64
        float s[4][4] = {};
        for (int kk = 0; kk < 64; kk++) {
            float qv[4], kv[4];
#pragma unroll
            for (int i = 0; i < 4; i++) qv[i] = Qs[r0 + i][kk];
#pragma unroll
            for (int j = 0; j < 4; j++) kv[j] = KPs[c0 + j][kk];
#pragma unroll
            for (int i = 0; i < 4; i++)
#pragma unroll
                for (int j = 0; j < 4; j++)
                    s[i][j] = fmaf(qv[i], kv[j], s[i][j]);
        }
        float qn[4], kn[4];
#pragma unroll
        for (int i = 0; i < 4; i++) qn[i] = Qn[r0 + i];
#pragma unroll
        for (int j = 0; j < 4; j++) kn[j] = Kn[c0 + j];

        // hyperbolic distance -> score
#pragma unroll
        for (int i = 0; i < 4; i++)
#pragma unroll
            for (int j = 0; j < 4; j++) {
                float dns = qn[i] - 2.f * s[i][j] + kn[j];
                float denom = fmaxf((1.f - c * qn[i]) * (1.f - c * kn[j]), EPS_);
                float arg = fmaxf(1.f + 2.f * c * dns / denom, 1.f + EPS_);
                float dist = acoshf(arg) / sc;
                s[i][j] = -bp * dist - ab;
            }

        // online softmax
        float mnew[4], alpha[4];
#pragma unroll
        for (int i = 0; i < 4; i++) {
            float rm = fmaxf(fmaxf(s[i][0], s[i][1]), fmaxf(s[i][2], s[i][3]));
#pragma unroll
            for (int mk = 1; mk < 16; mk <<= 1) rm = fmaxf(rm, __shfl_xor(rm, mk, 64));
            mnew[i] = fmaxf(m_i[i], rm);
            alpha[i] = expf(m_i[i] - mnew[i]);
        }
#pragma unroll
        for (int i = 0; i < 4; i++) {
            float rs = 0.f;
#pragma unroll
            for (int j = 0; j < 4; j++) { s[i][j] = expf(s[i][j] - mnew[i]); rs += s[i][j]; }
#pragma unroll
            for (int mk = 1; mk < 16; mk <<= 1) rs += __shfl_xor(rs, mk, 64);
            l_i[i] = l_i[i] * alpha[i] + rs;
            m_i[i] = mnew[i];
        }

        __syncthreads();   // all done reading KPs as K
#pragma unroll
        for (int i = 0; i < 4; i++)
#pragma unroll
            for (int j = 0; j < 4; j++) KPs[r0 + i][c0 + j] = s[i][j];
        __syncthreads();

        // O = O*alpha + P @ V
#pragma unroll
        for (int i = 0; i < 4; i++)
#pragma unroll
            for (int j = 0; j < 4; j++) O[i][j] *= alpha[i];
        for (int t = 0; t < 64; t++) {
            float pv[4], vv[4];
#pragma unroll
            for (int i = 0; i < 4; i++) pv[i] = KPs[r0 + i][t];
#pragma unroll
            for (int j = 0; j < 4; j++) vv[j] = Vs[t][c0 + j];
#pragma unroll
            for (int i = 0; i < 4; i++)
#pragma unroll
                for (int j = 0; j < 4; j++)
                    O[i][j] = fmaf(pv[i], vv[j], O[i][j]);
        }
    }

    // epilogue: out_tan = O/l; exp_map; log_map; write concat
    float ot[4][4];
#pragma unroll
    for (int i = 0; i < 4; i++) {
        float inv = 1.f / l_i[i];
#pragma unroll
        for (int j = 0; j < 4; j++) ot[i][j] = O[i][j] * inv;
    }
#pragma unroll
    for (int i = 0; i < 4; i++) {
        float t2 = 0.f;
#pragma unroll
        for (int j = 0; j < 4; j++) t2 += ot[i][j] * ot[i][j];
#pragma unroll
        for (int mk = 1; mk < 16; mk <<= 1) t2 += __shfl_xor(t2, mk, 64);
        float n = fmaxf(sqrtf(t2), EPS_);
        float fac = tanhf(sc * n) / (sc * n);      // exp_map
#pragma unroll
        for (int j = 0; j < 4; j++) ot[i][j] *= fac;
        float y2 = 0.f;
#pragma unroll
        for (int j = 0; j < 4; j++) y2 += ot[i][j] * ot[i][j];
#pragma unroll
        for (int mk = 1; mk < 16; mk <<= 1) y2 += __shfl_xor(y2, mk, 64);
        float yn = fmaxf(sqrtf(y2), EPS_);
        float ycl = fminf(yn, 1.f / sc - EPS_);
        float fac2 = atanhf(sc * ycl) / (sc * yn); // log_map
#pragma unroll
        for (int j = 0; j < 4; j++) ot[i][j] *= fac2;
    }
#pragma unroll
    for (int i = 0; i < 4; i++)
#pragma unroll
        for (int j = 0; j < 4; j++)
            concat[(size_t)(b * Ss + q0 + r0 + i) * Dd + h * DHh + c0 + j] = ot[i][j];
}

extern "C" void kernel_launch(void* const* d_in, const int* in_sizes, int n_in,
                              void* d_out, int out_size, void* d_ws, size_t ws_size,
                              hipStream_t stream)
{
    const float* x    = (const float*)d_in[0];
    const float* Wq   = (const float*)d_in[1];
    const float* Wk   = (const float*)d_in[2];
    const float* Wv   = (const float*)d_in[3];
    const float* Wo   = (const float*)d_in[4];
    const float* logc = (const float*)d_in[5];
    const float* beta = (const float*)d_in[6];
    const float* bias = (const float*)d_in[7];
    float* out = (float*)d_out;

    float* w   = (float*)d_ws;
    float* qt  = w;
    float* kt  = w + (size_t)2097152;
    float* vt  = w + (size_t)4194304;
    float* cc  = w + (size_t)6291456;
    float* qns = w + (size_t)8388608;
    float* kns = qns + 32768;

    // 1) projections (one dispatch, z selects W/out)
    gemm_nt<<<dim3(8, 16, 3), 256, 0, stream>>>(x, Wq, Wk, Wv, qt, kt, vt, 2048, 1024, 1024);
    // 2) hyperbolic maps (in-place)
    hyper_maps<<<dim3(8192, 3), 256, 0, stream>>>(qt, kt, vt, qt, kt, vt, qns, kns, logc);
    // 3) flash attention + exp/log map epilogue -> concat
    attn<<<dim3(16, 16, 2), 256, 0, stream>>>(qt, kt, vt, qns, kns, cc, logc, beta, bias);
    // 4) output projection
    gemm_nt<<<dim3(8, 16, 1), 256, 0, stream>>>(cc, Wo, Wo, Wo, out, out, out, 2048, 1024, 1024);
}

// Round 2
// 668.886 us; speedup vs baseline: 1.2071x; 1.2071x over previous
//
#include <hip/hip_runtime.h>
#include <math.h>

// HyperbolicMultiHeadAttention — round 1: MFMA bf16 flash attention.
// B=2, S=1024, D=1024, H=16, dh=64. GEMMs still fp32 (next round).
// ws layout (floats): qt[2M] kt[2M] vt[2M] concat[2M] qns[32K] kns[32K]

#define EPS_ 1e-5f

constexpr int Bb = 2, Ss = 1024, Dd = 1024, Hh = 16, DHh = 64;

typedef __attribute__((ext_vector_type(8))) short bf16x8;
typedef __attribute__((ext_vector_type(4))) float f32x4;

__device__ __forceinline__ float softplusf_(float x) {
    return (x > 20.f) ? x : log1pf(expf(x));
}

__device__ __forceinline__ float waveSum64(float v) {
#pragma unroll
    for (int m = 32; m >= 1; m >>= 1) v += __shfl_xor(v, m, 64);
    return v;
}

__device__ __forceinline__ short f2bf(float f) {
    union { float f; unsigned u; } v; v.f = f;
    unsigned r = v.u + 0x7FFFu + ((v.u >> 16) & 1u);   // RNE
    return (short)(r >> 16);
}
__device__ __forceinline__ unsigned pack2(float a, float b) {
    return (unsigned)(unsigned short)f2bf(a) | ((unsigned)(unsigned short)f2bf(b) << 16);
}

// ---------------- fp32 GEMM (unchanged this round) ----------------
// C[M,N] = A[M,K] @ B[N,K]^T. 128x128 tile, BK=8, 8x8/thread.
__global__ __launch_bounds__(256) void gemm_nt(
    const float* __restrict__ A,
    const float* __restrict__ B0, const float* __restrict__ B1, const float* __restrict__ B2,
    float* __restrict__ C0, float* __restrict__ C1, float* __restrict__ C2,
    int M, int N, int K)
{
    const float* Bp = (blockIdx.z == 0) ? B0 : (blockIdx.z == 1 ? B1 : B2);
    float* Cp = (blockIdx.z == 0) ? C0 : (blockIdx.z == 1 ? C1 : C2);
    __shared__ float As[8][128];
    __shared__ float Bs[8][128];
    const int tid = threadIdx.x;
    const int tx = tid & 15, ty = tid >> 4;
    const int bm = blockIdx.y * 128, bn = blockIdx.x * 128;
    const int lr = tid >> 1, lc = (tid & 1) << 2;
    float acc[8][8] = {};
    for (int k0 = 0; k0 < K; k0 += 8) {
        float4 a4 = *(const float4*)(A  + (size_t)(bm + lr) * K + k0 + lc);
        float4 b4 = *(const float4*)(Bp + (size_t)(bn + lr) * K + k0 + lc);
        __syncthreads();
        As[lc + 0][lr] = a4.x; As[lc + 1][lr] = a4.y; As[lc + 2][lr] = a4.z; As[lc + 3][lr] = a4.w;
        Bs[lc + 0][lr] = b4.x; Bs[lc + 1][lr] = b4.y; Bs[lc + 2][lr] = b4.z; Bs[lc + 3][lr] = b4.w;
        __syncthreads();
#pragma unroll
        for (int k = 0; k < 8; ++k) {
            float av[8], bv[8];
#pragma unroll
            for (int i = 0; i < 8; i++) av[i] = As[k][ty * 8 + i];
#pragma unroll
            for (int j = 0; j < 8; j++) bv[j] = Bs[k][tx * 8 + j];
#pragma unroll
            for (int i = 0; i < 8; i++)
#pragma unroll
                for (int j = 0; j < 8; j++)
                    acc[i][j] = fmaf(av[i], bv[j], acc[i][j]);
        }
    }
#pragma unroll
    for (int i = 0; i < 8; i++) {
        float4 o0 = make_float4(acc[i][0], acc[i][1], acc[i][2], acc[i][3]);
        float4 o1 = make_float4(acc[i][4], acc[i][5], acc[i][6], acc[i][7]);
        float* cr = Cp + (size_t)(bm + ty * 8 + i) * N + bn + tx * 8;
        *(float4*)cr = o0;
        *(float4*)(cr + 4) = o1;
    }
}

// ---------------- hyperbolic maps (unchanged) ----------------
__global__ __launch_bounds__(256) void hyper_maps(
    const float* __restrict__ qt, const float* __restrict__ kt, const float* __restrict__ vt,
    float* __restrict__ qh, float* __restrict__ kh, float* __restrict__ vtan,
    float* __restrict__ qns, float* __restrict__ kns,
    const float* __restrict__ p_logc)
{
    const float c = softplusf_(p_logc[0]);
    const float sc = sqrtf(c);
    const int which = blockIdx.y;
    const int wv = threadIdx.x >> 6, lane = threadIdx.x & 63;
    const int vec = blockIdx.x * 4 + wv;
    const int row = vec >> 4, h = vec & 15;
    const size_t off = (size_t)row * Dd + h * DHh + lane;

    const float* src = (which == 0) ? qt : (which == 1) ? kt : vt;
    float x = src[off];
    float ns = waveSum64(x * x);
    float n = fmaxf(sqrtf(ns), EPS_);
    float th = tanhf(sc * n);
    float y = x * (th / (sc * n));

    if (which == 0) {
        qh[off] = y;
        float yns = waveSum64(y * y);
        if (lane == 0) qns[vec] = yns;
    } else if (which == 1) {
        kh[off] = y;
        float yns = waveSum64(y * y);
        if (lane == 0) kns[vec] = yns;
    } else {
        float yn2 = waveSum64(y * y);
        float yn = fmaxf(sqrtf(yn2), EPS_);
        float ycl = fminf(yn, 1.f / sc - EPS_);
        float fac = atanhf(sc * ycl) / (sc * yn);
        vtan[off] = y * fac;
    }
}

// ---------------- MFMA flash attention ----------------
// Block = 256 threads = 4 waves; block handles (b, h, 64-row q-tile).
// Wave w owns S/O rows [16w, 16w+16). All LDS tiles bf16, stride 72
// shorts (144B = 36 words -> even bank spread for b128 fragment reads).
__global__ __launch_bounds__(256) void attn_mfma(
    const float* __restrict__ qh, const float* __restrict__ kh, const float* __restrict__ vtan,
    const float* __restrict__ qns, const float* __restrict__ kns,
    float* __restrict__ concat,
    const float* __restrict__ p_logc, const float* __restrict__ p_beta,
    const float* __restrict__ p_bias)
{
    const float c = softplusf_(p_logc[0]);
    const float sc = sqrtf(c);
    const float bp = softplusf_(p_beta[0]);
    const float ab = p_bias[0];

    const int h = blockIdx.y, b = blockIdx.z, q0 = blockIdx.x * 64;

    __shared__ short Qs[64][72];   // [q][d]
    __shared__ short Ks[64][72];   // [t][d]
    __shared__ short Vt[64][72];   // [d][t]  (V transposed)
    __shared__ short Ps[64][72];   // [q][t]
    __shared__ float Qn[64], Kn[64];

    const int tid = threadIdx.x;
    const int wave = tid >> 6, lane = tid & 63;
    const int quad = lane >> 4, l15 = lane & 15;

    // ---- stage Q tile (fp32 -> bf16), row pattern ----
    {
        int r = tid >> 2, cb = (tid & 3) << 4;
        const float* src = qh + (size_t)(b * Ss + q0 + r) * Dd + h * DHh + cb;
        float4 a0 = *(const float4*)(src + 0);
        float4 a1 = *(const float4*)(src + 4);
        float4 a2 = *(const float4*)(src + 8);
        float4 a3 = *(const float4*)(src + 12);
        unsigned* dst = (unsigned*)&Qs[r][cb];
        dst[0] = pack2(a0.x, a0.y); dst[1] = pack2(a0.z, a0.w);
        dst[2] = pack2(a1.x, a1.y); dst[3] = pack2(a1.z, a1.w);
        dst[4] = pack2(a2.x, a2.y); dst[5] = pack2(a2.z, a2.w);
        dst[6] = pack2(a3.x, a3.y); dst[7] = pack2(a3.z, a3.w);
    }
    if (tid < 64) Qn[tid] = qns[(size_t)(b * Ss + q0 + tid) * Hh + h];
    __syncthreads();

    float qn_r[4];
#pragma unroll
    for (int r = 0; r < 4; r++) qn_r[r] = Qn[wave * 16 + quad * 4 + r];

    // Q A-fragments (static across chunks): A[m=l15][k=quad*8+j]
    bf16x8 qa0 = *(const bf16x8*)&Qs[wave * 16 + l15][quad * 8];
    bf16x8 qa1 = *(const bf16x8*)&Qs[wave * 16 + l15][32 + quad * 8];

    float m_i[4], l_i[4];
    f32x4 O4[4];  // [ntile(d)] x 4 regs (rows)
#pragma unroll
    for (int r = 0; r < 4; r++) { m_i[r] = -1e30f; l_i[r] = 0.f; }
#pragma unroll
    for (int nt = 0; nt < 4; nt++) O4[nt] = (f32x4){0.f, 0.f, 0.f, 0.f};

    for (int t0 = 0; t0 < Ss; t0 += 64) {
        __syncthreads();   // all reads of Ks/Vt from previous chunk done
        // ---- stage K rows (fp32 -> bf16) ----
        {
            int r = tid >> 2, cb = (tid & 3) << 4;
            const float* src = kh + (size_t)(b * Ss + t0 + r) * Dd + h * DHh + cb;
            float4 a0 = *(const float4*)(src + 0);
            float4 a1 = *(const float4*)(src + 4);
            float4 a2 = *(const float4*)(src + 8);
            float4 a3 = *(const float4*)(src + 12);
            unsigned* dst = (unsigned*)&Ks[r][cb];
            dst[0] = pack2(a0.x, a0.y); dst[1] = pack2(a0.z, a0.w);
            dst[2] = pack2(a1.x, a1.y); dst[3] = pack2(a1.z, a1.w);
            dst[4] = pack2(a2.x, a2.y); dst[5] = pack2(a2.z, a2.w);
            dst[6] = pack2(a3.x, a3.y); dst[7] = pack2(a3.z, a3.w);
        }
        // ---- stage V transposed: coalesced column dword reads ----
        {
            int d = tid & 63, tq = (tid >> 6) * 16;
            const float* base = vtan + (size_t)(b * Ss + t0 + tq) * Dd + h * DHh + d;
#pragma unroll
            for (int u = 0; u < 16; u++)
                Vt[d][tq + u] = f2bf(base[(size_t)u * Dd]);
        }
        if (tid < 64) Kn[tid] = kns[(size_t)(b * Ss + t0 + tid) * Hh + h];
        __syncthreads();

        // ---- S = Q @ K^T via MFMA ----
        f32x4 acc[4];
#pragma unroll
        for (int nt = 0; nt < 4; nt++) {
            bf16x8 b0 = *(const bf16x8*)&Ks[nt * 16 + l15][quad * 8];
            bf16x8 b1 = *(const bf16x8*)&Ks[nt * 16 + l15][32 + quad * 8];
            f32x4 a = (f32x4){0.f, 0.f, 0.f, 0.f};
            a = __builtin_amdgcn_mfma_f32_16x16x32_bf16(qa0, b0, a, 0, 0, 0);
            a = __builtin_amdgcn_mfma_f32_16x16x32_bf16(qa1, b1, a, 0, 0, 0);
            acc[nt] = a;
        }

        // ---- hyperbolic distance -> scores (fp32) ----
        float kn_c[4];
#pragma unroll
        for (int nt = 0; nt < 4; nt++) kn_c[nt] = Kn[nt * 16 + l15];
        float s[4][4];  // [nt][reg]
#pragma unroll
        for (int nt = 0; nt < 4; nt++) {
            float omk = 1.f - c * kn_c[nt];
#pragma unroll
            for (int r = 0; r < 4; r++) {
                float dns = qn_r[r] - 2.f * acc[nt][r] + kn_c[nt];
                float denom = fmaxf((1.f - c * qn_r[r]) * omk, EPS_);
                float arg = fmaxf(1.f + 2.f * c * dns / denom, 1.f + EPS_);
                s[nt][r] = -bp * (acoshf(arg) / sc) - ab;
            }
        }

        // ---- online softmax (row stats across 16 lanes x 4 ntiles) ----
        float alpha[4];
#pragma unroll
        for (int r = 0; r < 4; r++) {
            float rm = fmaxf(fmaxf(s[0][r], s[1][r]), fmaxf(s[2][r], s[3][r]));
#pragma unroll
            for (int mk = 1; mk < 16; mk <<= 1) rm = fmaxf(rm, __shfl_xor(rm, mk, 64));
            float mnew = fmaxf(m_i[r], rm);
            alpha[r] = expf(m_i[r] - mnew);
            float rs = 0.f;
#pragma unroll
            for (int nt = 0; nt < 4; nt++) { s[nt][r] = expf(s[nt][r] - mnew); rs += s[nt][r]; }
#pragma unroll
            for (int mk = 1; mk < 16; mk <<= 1) rs += __shfl_xor(rs, mk, 64);
            l_i[r] = l_i[r] * alpha[r] + rs;
            m_i[r] = mnew;
        }

        // ---- P -> LDS (C-layout -> A-layout round trip), bf16 ----
#pragma unroll
        for (int nt = 0; nt < 4; nt++)
#pragma unroll
            for (int r = 0; r < 4; r++)
                Ps[wave * 16 + quad * 4 + r][nt * 16 + l15] = f2bf(s[nt][r]);

        // ---- O = O*alpha + P @ V ----
#pragma unroll
        for (int nt = 0; nt < 4; nt++)
#pragma unroll
            for (int r = 0; r < 4; r++) O4[nt][r] *= alpha[r];

        bf16x8 pa0 = *(const bf16x8*)&Ps[wave * 16 + l15][quad * 8];
        bf16x8 pa1 = *(const bf16x8*)&Ps[wave * 16 + l15][32 + quad * 8];
#pragma unroll
        for (int nt = 0; nt < 4; nt++) {
            bf16x8 vb0 = *(const bf16x8*)&Vt[nt * 16 + l15][quad * 8];
            bf16x8 vb1 = *(const bf16x8*)&Vt[nt * 16 + l15][32 + quad * 8];
            O4[nt] = __builtin_amdgcn_mfma_f32_16x16x32_bf16(pa0, vb0, O4[nt], 0, 0, 0);
            O4[nt] = __builtin_amdgcn_mfma_f32_16x16x32_bf16(pa1, vb1, O4[nt], 0, 0, 0);
        }
    }

    // ---- epilogue: /l, exp_map, log_map, store concat ----
    float ot[4][4];  // [nt][reg]
#pragma unroll
    for (int r = 0; r < 4; r++) {
        float linv = 1.f / l_i[r];
#pragma unroll
        for (int nt = 0; nt < 4; nt++) ot[nt][r] = O4[nt][r] * linv;
    }
#pragma unroll
    for (int r = 0; r < 4; r++) {
        float t2 = 0.f;
#pragma unroll
        for (int nt = 0; nt < 4; nt++) t2 += ot[nt][r] * ot[nt][r];
#pragma unroll
        for (int mk = 1; mk < 16; mk <<= 1) t2 += __shfl_xor(t2, mk, 64);
        float n = fmaxf(sqrtf(t2), EPS_);
        float fac = tanhf(sc * n) / (sc * n);            // exp_map factor
        float y2 = t2 * fac * fac;
        float yn = fmaxf(sqrtf(y2), EPS_);
        float ycl = fminf(yn, 1.f / sc - EPS_);
        float fac2 = atanhf(sc * ycl) / (sc * yn);       // log_map factor
        float tot = fac * fac2;
#pragma unroll
        for (int nt = 0; nt < 4; nt++) ot[nt][r] *= tot;
    }
#pragma unroll
    for (int nt = 0; nt < 4; nt++)
#pragma unroll
        for (int r = 0; r < 4; r++)
            concat[(size_t)(b * Ss + q0 + wave * 16 + quad * 4 + r) * Dd
                   + h * DHh + nt * 16 + l15] = ot[nt][r];
}

extern "C" void kernel_launch(void* const* d_in, const int* in_sizes, int n_in,
                              void* d_out, int out_size, void* d_ws, size_t ws_size,
                              hipStream_t stream)
{
    const float* x    = (const float*)d_in[0];
    const float* Wq   = (const float*)d_in[1];
    const float* Wk   = (const float*)d_in[2];
    const float* Wv   = (const float*)d_in[3];
    const float* Wo   = (const float*)d_in[4];
    const float* logc = (const float*)d_in[5];
    const float* beta = (const float*)d_in[6];
    const float* bias = (const float*)d_in[7];
    float* out = (float*)d_out;

    float* w   = (float*)d_ws;
    float* qt  = w;
    float* kt  = w + (size_t)2097152;
    float* vt  = w + (size_t)4194304;
    float* cc  = w + (size_t)6291456;
    float* qns = w + (size_t)8388608;
    float* kns = qns + 32768;

    gemm_nt<<<dim3(8, 16, 3), 256, 0, stream>>>(x, Wq, Wk, Wv, qt, kt, vt, 2048, 1024, 1024);
    hyper_maps<<<dim3(8192, 3), 256, 0, stream>>>(qt, kt, vt, qt, kt, vt, qns, kns, logc);
    attn_mfma<<<dim3(16, 16, 2), 256, 0, stream>>>(qt, kt, vt, qns, kns, cc, logc, beta, bias);
    gemm_nt<<<dim3(8, 16, 1), 256, 0, stream>>>(cc, Wo, Wo, Wo, out, out, out, 2048, 1024, 1024);
}

// Round 3
// 265.939 us; speedup vs baseline: 3.0361x; 2.5152x over previous
//
#include <hip/hip_runtime.h>
#include <math.h>

// HyperbolicMultiHeadAttention — round 2:
//  * hi/lo-split bf16 MFMA GEMMs (QKV: 3-term, fp32-grade; out-proj: single bf16)
//  * attention scores in log space: p = u^(-beta/sc), u = arg+sqrt(arg^2-1);
//    no online max (scores bounded in [-12, 0]), attention_bias dropped (exact
//    softmax shift invariance). K/V staged from pre-converted bf16.
// B=2, S=1024, D=1024, H=16, dh=64.

#define EPS_ 1e-5f

constexpr int Bb = 2, Ss = 1024, Dd = 1024, Hh = 16, DHh = 64;

typedef __attribute__((ext_vector_type(8))) short bf16x8;
typedef __attribute__((ext_vector_type(4))) float f32x4;

__device__ __forceinline__ float softplusf_(float x) {
    return (x > 20.f) ? x : log1pf(expf(x));
}
__device__ __forceinline__ float waveSum64(float v) {
#pragma unroll
    for (int m = 32; m >= 1; m >>= 1) v += __shfl_xor(v, m, 64);
    return v;
}
__device__ __forceinline__ short f2bf(float f) {
    union { float f; unsigned u; } v; v.f = f;
    unsigned r = v.u + 0x7FFFu + ((v.u >> 16) & 1u);   // RNE
    return (short)(r >> 16);
}
__device__ __forceinline__ float bf2f(short h) {
    union { unsigned u; float f; } v; v.u = ((unsigned)(unsigned short)h) << 16;
    return v.f;
}
__device__ __forceinline__ unsigned pks(short a, short b) {
    return (unsigned)(unsigned short)a | ((unsigned)(unsigned short)b << 16);
}

// ---------------- split fp32 -> bf16 hi (+ lo residual) ----------------
// ranges in float4 groups: x 524288 | Wq 262144 | Wk | Wv | Wo(hi only)
__global__ __launch_bounds__(256) void split_all(
    const float* __restrict__ x,  const float* __restrict__ Wq,
    const float* __restrict__ Wk, const float* __restrict__ Wv,
    const float* __restrict__ Wo,
    short* __restrict__ xhi, short* __restrict__ xlo,
    short* __restrict__ wqh, short* __restrict__ wql,
    short* __restrict__ wkh, short* __restrict__ wkl,
    short* __restrict__ wvh, short* __restrict__ wvl,
    short* __restrict__ woh)
{
    int g = blockIdx.x * 256 + threadIdx.x;
    const float* src; short* hi; short* lo; int base;
    if (g < 524288)       { src = x;  hi = xhi; lo = xlo; base = g; }
    else if (g < 786432)  { src = Wq; hi = wqh; lo = wql; base = g - 524288; }
    else if (g < 1048576) { src = Wk; hi = wkh; lo = wkl; base = g - 786432; }
    else if (g < 1310720) { src = Wv; hi = wvh; lo = wvl; base = g - 1048576; }
    else                  { src = Wo; hi = woh; lo = (short*)0; base = g - 1310720; }
    float4 v = *(const float4*)(src + (size_t)base * 4);
    short h0 = f2bf(v.x), h1 = f2bf(v.y), h2 = f2bf(v.z), h3 = f2bf(v.w);
    uint2 hp; hp.x = pks(h0, h1); hp.y = pks(h2, h3);
    *(uint2*)(hi + (size_t)base * 4) = hp;
    if (lo) {
        short l0 = f2bf(v.x - bf2f(h0)), l1 = f2bf(v.y - bf2f(h1));
        short l2 = f2bf(v.z - bf2f(h2)), l3 = f2bf(v.w - bf2f(h3));
        uint2 lp; lp.x = pks(l0, l1); lp.y = pks(l2, l3);
        *(uint2*)(lo + (size_t)base * 4) = lp;
    }
}

// ---------------- bf16 MFMA NT GEMM: C[M,N] = A[M,K] @ B[N,K]^T ----------------
// 128x128 tile, BK=32, 4 waves (wave = 32 rows x 128 cols), fp32 C out.
// HILO=1: C = Ah*Bh + Ah*Bl + Al*Bh (hi/lo split operands).
template<int HILO>
__global__ __launch_bounds__(256) void gemm_bt(
    const short* __restrict__ Ahp, const short* __restrict__ Alp,
    const short* __restrict__ Bh0, const short* __restrict__ Bl0,
    const short* __restrict__ Bh1, const short* __restrict__ Bl1,
    const short* __restrict__ Bh2, const short* __restrict__ Bl2,
    float* __restrict__ C0, float* __restrict__ C1, float* __restrict__ C2,
    int M, int N, int K)
{
    const short* Bh = (blockIdx.z == 0) ? Bh0 : (blockIdx.z == 1 ? Bh1 : Bh2);
    const short* Bl = (blockIdx.z == 0) ? Bl0 : (blockIdx.z == 1 ? Bl1 : Bl2);
    float* Cp = (blockIdx.z == 0) ? C0 : (blockIdx.z == 1 ? C1 : C2);

    __shared__ short sm[(HILO ? 4 : 2) * 4096];
    short* Ahs = sm;
    short* Bhs = sm + 4096;
    short* Als = HILO ? (sm + 8192)  : sm;
    short* Bls = HILO ? (sm + 12288) : sm;

    const int tid = threadIdx.x;
    const int wv = tid >> 6, l15 = tid & 15, quad = (tid & 63) >> 4;
    const int bm = blockIdx.y * 128, bn = blockIdx.x * 128;
    const int r0 = tid >> 2, q4 = (tid & 3) * 8;      // staging: row r0/r0+64, 8 shorts

    f32x4 acc[2][8];
#pragma unroll
    for (int i = 0; i < 2; i++)
#pragma unroll
        for (int j = 0; j < 8; j++) acc[i][j] = (f32x4){0.f, 0.f, 0.f, 0.f};

    const size_t arow0 = (size_t)(bm + r0) * K, arow1 = (size_t)(bm + r0 + 64) * K;
    const size_t brow0 = (size_t)(bn + r0) * K, brow1 = (size_t)(bn + r0 + 64) * K;

    for (int k0 = 0; k0 < K; k0 += 32) {
        bf16x8 ah0 = *(const bf16x8*)(Ahp + arow0 + k0 + q4);
        bf16x8 ah1 = *(const bf16x8*)(Ahp + arow1 + k0 + q4);
        bf16x8 bh0 = *(const bf16x8*)(Bh  + brow0 + k0 + q4);
        bf16x8 bh1 = *(const bf16x8*)(Bh  + brow1 + k0 + q4);
        bf16x8 al0, al1, bl0, bl1;
        if (HILO) {
            al0 = *(const bf16x8*)(Alp + arow0 + k0 + q4);
            al1 = *(const bf16x8*)(Alp + arow1 + k0 + q4);
            bl0 = *(const bf16x8*)(Bl  + brow0 + k0 + q4);
            bl1 = *(const bf16x8*)(Bl  + brow1 + k0 + q4);
        }
        __syncthreads();
        *(bf16x8*)&Ahs[r0 * 32 + q4]        = ah0;
        *(bf16x8*)&Ahs[(r0 + 64) * 32 + q4] = ah1;
        *(bf16x8*)&Bhs[r0 * 32 + q4]        = bh0;
        *(bf16x8*)&Bhs[(r0 + 64) * 32 + q4] = bh1;
        if (HILO) {
            *(bf16x8*)&Als[r0 * 32 + q4]        = al0;
            *(bf16x8*)&Als[(r0 + 64) * 32 + q4] = al1;
            *(bf16x8*)&Bls[r0 * 32 + q4]        = bl0;
            *(bf16x8*)&Bls[(r0 + 64) * 32 + q4] = bl1;
        }
        __syncthreads();

        const int ab = (wv * 32 + l15) * 32 + quad * 8;
        bf16x8 fa0 = *(const bf16x8*)&Ahs[ab];
        bf16x8 fa1 = *(const bf16x8*)&Ahs[ab + 16 * 32];
        bf16x8 la0, la1;
        if (HILO) { la0 = *(const bf16x8*)&Als[ab]; la1 = *(const bf16x8*)&Als[ab + 16 * 32]; }
#pragma unroll
        for (int nt = 0; nt < 8; nt++) {
            const int bb = (nt * 16 + l15) * 32 + quad * 8;
            bf16x8 fb = *(const bf16x8*)&Bhs[bb];
            acc[0][nt] = __builtin_amdgcn_mfma_f32_16x16x32_bf16(fa0, fb, acc[0][nt], 0, 0, 0);
            acc[1][nt] = __builtin_amdgcn_mfma_f32_16x16x32_bf16(fa1, fb, acc[1][nt], 0, 0, 0);
            if (HILO) {
                bf16x8 lb = *(const bf16x8*)&Bls[bb];
                acc[0][nt] = __builtin_amdgcn_mfma_f32_16x16x32_bf16(fa0, lb, acc[0][nt], 0, 0, 0);
                acc[1][nt] = __builtin_amdgcn_mfma_f32_16x16x32_bf16(fa1, lb, acc[1][nt], 0, 0, 0);
                acc[0][nt] = __builtin_amdgcn_mfma_f32_16x16x32_bf16(la0, fb, acc[0][nt], 0, 0, 0);
                acc[1][nt] = __builtin_amdgcn_mfma_f32_16x16x32_bf16(la1, fb, acc[1][nt], 0, 0, 0);
            }
        }
    }
#pragma unroll
    for (int mt = 0; mt < 2; mt++)
#pragma unroll
        for (int nt = 0; nt < 8; nt++)
#pragma unroll
            for (int r = 0; r < 4; r++)
                Cp[(size_t)(bm + wv * 32 + mt * 16 + quad * 4 + r) * N + bn + nt * 16 + l15]
                    = acc[mt][nt][r];
}

// ---------------- hyperbolic maps: fp32 in, bf16 out + fp32 norms ----------------
__global__ __launch_bounds__(256) void hyper_maps(
    const float* __restrict__ qt, const float* __restrict__ kt, const float* __restrict__ vt,
    short* __restrict__ qh, short* __restrict__ kh, short* __restrict__ vth,
    float* __restrict__ qns, float* __restrict__ kns,
    const float* __restrict__ p_logc)
{
    const float c = softplusf_(p_logc[0]);
    const float sc = sqrtf(c);
    const int which = blockIdx.y;
    const int wv = threadIdx.x >> 6, lane = threadIdx.x & 63;
    const int vec = blockIdx.x * 4 + wv;
    const int row = vec >> 4, h = vec & 15;
    const size_t off = (size_t)row * Dd + h * DHh + lane;

    const float* src = (which == 0) ? qt : (which == 1) ? kt : vt;
    float x = src[off];
    float ns = waveSum64(x * x);
    float n = fmaxf(sqrtf(ns), EPS_);
    float th = tanhf(sc * n);
    float y = x * (th / (sc * n));                    // exp_map

    if (which == 0) {
        qh[off] = f2bf(y);
        float yns = waveSum64(y * y);
        if (lane == 0) qns[vec] = yns;
    } else if (which == 1) {
        kh[off] = f2bf(y);
        float yns = waveSum64(y * y);
        if (lane == 0) kns[vec] = yns;
    } else {
        float yn2 = waveSum64(y * y);
        float yn = fmaxf(sqrtf(yn2), EPS_);
        float ycl = fminf(yn, 1.f / sc - EPS_);
        float fac = atanhf(sc * ycl) / (sc * yn);     // log_map
        vth[off] = f2bf(y * fac);
    }
}

// ---------------- MFMA flash attention, log-space scores ----------------
__global__ __launch_bounds__(256) void attn_mfma(
    const short* __restrict__ qh, const short* __restrict__ kh, const short* __restrict__ vth,
    const float* __restrict__ qns, const float* __restrict__ kns,
    short* __restrict__ ccb,
    const float* __restrict__ p_logc, const float* __restrict__ p_beta)
{
    const float c = softplusf_(p_logc[0]);
    const float sc = sqrtf(c);
    const float bp = softplusf_(p_beta[0]);
    const float kcoef = bp / sc;
    const float twoC = 2.f * c;

    const int h = blockIdx.y, b = blockIdx.z, q0 = blockIdx.x * 64;

    __shared__ short Qs[64][72];
    __shared__ short Ks[64][72];
    __shared__ short Vt[64][72];   // V transposed [d][t]
    __shared__ short Ps[64][72];
    __shared__ float Qn[64], Kn[64];

    const int tid = threadIdx.x;
    const int wave = tid >> 6, lane = tid & 63;
    const int quad = lane >> 4, l15 = lane & 15;

    {   // stage Q (bf16 copy)
        int r = tid >> 2, cb = (tid & 3) << 4;
        const short* src = qh + (size_t)(b * Ss + q0 + r) * Dd + h * DHh + cb;
        *(bf16x8*)&Qs[r][cb]     = *(const bf16x8*)(src);
        *(bf16x8*)&Qs[r][cb + 8] = *(const bf16x8*)(src + 8);
    }
    if (tid < 64) Qn[tid] = qns[(size_t)(b * Ss + q0 + tid) * Hh + h];
    __syncthreads();

    float qn_r[4], rq[4], irq[4];
#pragma unroll
    for (int r = 0; r < 4; r++) {
        qn_r[r] = Qn[wave * 16 + quad * 4 + r];
        rq[r] = 1.f - c * qn_r[r];
        irq[r] = 1.f / rq[r];
    }

    bf16x8 qa0 = *(const bf16x8*)&Qs[wave * 16 + l15][quad * 8];
    bf16x8 qa1 = *(const bf16x8*)&Qs[wave * 16 + l15][32 + quad * 8];

    float lac[4] = {0.f, 0.f, 0.f, 0.f};
    f32x4 O4[4];
#pragma unroll
    for (int nt = 0; nt < 4; nt++) O4[nt] = (f32x4){0.f, 0.f, 0.f, 0.f};

    for (int t0 = 0; t0 < Ss; t0 += 64) {
        __syncthreads();
        {   // stage K rows (bf16 copy)
            int r = tid >> 2, cb = (tid & 3) << 4;
            const short* src = kh + (size_t)(b * Ss + t0 + r) * Dd + h * DHh + cb;
            *(bf16x8*)&Ks[r][cb]     = *(const bf16x8*)(src);
            *(bf16x8*)&Ks[r][cb + 8] = *(const bf16x8*)(src + 8);
        }
        {   // stage V transposed (scalar shorts)
            int d = tid & 63, tq = (tid >> 6) * 16;
            const short* base = vth + (size_t)(b * Ss + t0 + tq) * Dd + h * DHh + d;
#pragma unroll
            for (int u = 0; u < 16; u++)
                Vt[d][tq + u] = base[(size_t)u * Dd];
        }
        if (tid < 64) Kn[tid] = kns[(size_t)(b * Ss + t0 + tid) * Hh + h];
        __syncthreads();

        // S = Q @ K^T
        f32x4 acc[4];
#pragma unroll
        for (int nt = 0; nt < 4; nt++) {
            bf16x8 b0 = *(const bf16x8*)&Ks[nt * 16 + l15][quad * 8];
            bf16x8 b1 = *(const bf16x8*)&Ks[nt * 16 + l15][32 + quad * 8];
            f32x4 a = (f32x4){0.f, 0.f, 0.f, 0.f};
            a = __builtin_amdgcn_mfma_f32_16x16x32_bf16(qa0, b0, a, 0, 0, 0);
            a = __builtin_amdgcn_mfma_f32_16x16x32_bf16(qa1, b1, a, 0, 0, 0);
            acc[nt] = a;
        }

        // p = u^(-bp/sc), u = arg + sqrt(arg^2-1);  no max-tracking needed.
        float kn_c[4], ick[4];
#pragma unroll
        for (int nt = 0; nt < 4; nt++) {
            kn_c[nt] = Kn[nt * 16 + l15];
            ick[nt] = 1.f / (1.f - c * kn_c[nt]);
        }
        float s[4][4];
#pragma unroll
        for (int nt = 0; nt < 4; nt++) {
            float ckn = 1.f - c * kn_c[nt];
#pragma unroll
            for (int r = 0; r < 4; r++) {
                float dns = qn_r[r] + kn_c[nt] - 2.f * acc[nt][r];
                float pr  = rq[r] * ckn;
                float invden = (pr > EPS_) ? irq[r] * ick[nt] : 1e5f;
                float arg = fmaxf(fmaf(twoC * invden, dns, 1.f), 1.f + EPS_);
                float tt  = fmaf(arg, arg, -1.f);
                float u   = arg + sqrtf(tt);
                float p   = __expf(-kcoef * __logf(u));
                s[nt][r] = p;
                lac[r] += p;
            }
        }

        __syncthreads();
#pragma unroll
        for (int nt = 0; nt < 4; nt++)
#pragma unroll
            for (int r = 0; r < 4; r++)
                Ps[wave * 16 + quad * 4 + r][nt * 16 + l15] = f2bf(s[nt][r]);
        __syncthreads();

        bf16x8 pa0 = *(const bf16x8*)&Ps[wave * 16 + l15][quad * 8];
        bf16x8 pa1 = *(const bf16x8*)&Ps[wave * 16 + l15][32 + quad * 8];
#pragma unroll
        for (int nt = 0; nt < 4; nt++) {
            bf16x8 vb0 = *(const bf16x8*)&Vt[nt * 16 + l15][quad * 8];
            bf16x8 vb1 = *(const bf16x8*)&Vt[nt * 16 + l15][32 + quad * 8];
            O4[nt] = __builtin_amdgcn_mfma_f32_16x16x32_bf16(pa0, vb0, O4[nt], 0, 0, 0);
            O4[nt] = __builtin_amdgcn_mfma_f32_16x16x32_bf16(pa1, vb1, O4[nt], 0, 0, 0);
        }
    }

    // final softmax normalization (sum across 16 lanes)
    float linv[4];
#pragma unroll
    for (int r = 0; r < 4; r++) {
        float ls = lac[r];
#pragma unroll
        for (int mk = 1; mk < 16; mk <<= 1) ls += __shfl_xor(ls, mk, 64);
        linv[r] = 1.f / ls;
    }

    float ot[4][4];
#pragma unroll
    for (int r = 0; r < 4; r++)
#pragma unroll
        for (int nt = 0; nt < 4; nt++) ot[nt][r] = O4[nt][r] * linv[r];
#pragma unroll
    for (int r = 0; r < 4; r++) {
        float t2 = 0.f;
#pragma unroll
        for (int nt = 0; nt < 4; nt++) t2 += ot[nt][r] * ot[nt][r];
#pragma unroll
        for (int mk = 1; mk < 16; mk <<= 1) t2 += __shfl_xor(t2, mk, 64);
        float n = fmaxf(sqrtf(t2), EPS_);
        float fac = tanhf(sc * n) / (sc * n);          // exp_map
        float y2 = t2 * fac * fac;
        float yn = fmaxf(sqrtf(y2), EPS_);
        float ycl = fminf(yn, 1.f / sc - EPS_);
        float fac2 = atanhf(sc * ycl) / (sc * yn);     // log_map
        float tot = fac * fac2;
#pragma unroll
        for (int nt = 0; nt < 4; nt++) ot[nt][r] *= tot;
    }
#pragma unroll
    for (int nt = 0; nt < 4; nt++)
#pragma unroll
        for (int r = 0; r < 4; r++)
            ccb[(size_t)(b * Ss + q0 + wave * 16 + quad * 4 + r) * Dd
                + h * DHh + nt * 16 + l15] = f2bf(ot[nt][r]);
}

extern "C" void kernel_launch(void* const* d_in, const int* in_sizes, int n_in,
                              void* d_out, int out_size, void* d_ws, size_t ws_size,
                              hipStream_t stream)
{
    const float* x    = (const float*)d_in[0];
    const float* Wq   = (const float*)d_in[1];
    const float* Wk   = (const float*)d_in[2];
    const float* Wv   = (const float*)d_in[3];
    const float* Wo   = (const float*)d_in[4];
    const float* logc = (const float*)d_in[5];
    const float* beta = (const float*)d_in[6];
    float* out = (float*)d_out;

    const size_t M2 = 2097152, M1 = 1048576;
    float* w   = (float*)d_ws;
    float* qt  = w;                       // 2M f  (reused as ccb later)
    float* kt  = w + M2;                  // 2M f
    float* vt  = w + 2 * M2;              // 2M f
    short* qhB = (short*)(w + 3 * M2);    // 2M s
    short* khB = qhB + M2;                // 2M s
    short* vtB = qhB + 2 * M2;            // 2M s
    float* qns = (float*)(qhB + 3 * M2);  // 32K f
    float* kns = qns + 32768;             // 32K f
    short* xhi = (short*)(kns + 32768);   // 2M s
    short* xlo = xhi + M2;                // 2M s
    short* wqh = xlo + M2;                // 1M s each below
    short* wql = wqh + M1;
    short* wkh = wql + M1;
    short* wkl = wkh + M1;
    short* wvh = wkl + M1;
    short* wvl = wvh + M1;
    short* woh = wvl + M1;
    short* ccb = (short*)w;               // alias over qt (dead after hyper_maps)

    // 1) split x and weights into bf16 hi/lo
    split_all<<<dim3(6144), 256, 0, stream>>>(x, Wq, Wk, Wv, Wo,
        xhi, xlo, wqh, wql, wkh, wkl, wvh, wvl, woh);
    // 2) QKV projections (hi/lo 3-term MFMA)
    gemm_bt<1><<<dim3(8, 16, 3), 256, 0, stream>>>(xhi, xlo,
        wqh, wql, wkh, wkl, wvh, wvl, qt, kt, vt, 2048, 1024, 1024);
    // 3) hyperbolic maps -> bf16 q_h/k_h/v_tan + fp32 norms
    hyper_maps<<<dim3(8192, 3), 256, 0, stream>>>(qt, kt, vt, qhB, khB, vtB, qns, kns, logc);
    // 4) flash attention (log-space scores) -> bf16 concat
    attn_mfma<<<dim3(16, 16, 2), 256, 0, stream>>>(qhB, khB, vtB, qns, kns, ccb, logc, beta);
    // 5) output projection (single bf16 MFMA)
    gemm_bt<0><<<dim3(8, 16, 1), 256, 0, stream>>>(ccb, ccb,
        woh, woh, woh, woh, woh, woh, out, out, out, 2048, 1024, 1024);
}

// Round 4
// 265.802 us; speedup vs baseline: 3.0377x; 1.0005x over previous
//
#include <hip/hip_runtime.h>
#include <math.h>

// HyperbolicMultiHeadAttention — round 4:
//  * single-bf16 QKV GEMM (hi/lo dropped: EPS-clamped denominators + tanh
//    saturation make scores insensitive to q/k norm error; dot error ~8e-4)
//  * hyper maps fused into GEMM epilogue (writes bf16 qh/kh, transposed vtT
//    [b,h,d,s], transposed norms [b,h,s])
//  * barrier-free attention: Q/K/V MFMA fragments loaded directly from
//    global (L2-resident), P round-trip through wave-private LDS only.
// B=2, S=1024, D=1024, H=16, dh=64.

#define EPS_ 1e-5f

constexpr int Ss = 1024, Dd = 1024, Hh = 16, DHh = 64;

typedef __attribute__((ext_vector_type(8))) short bf16x8;
typedef __attribute__((ext_vector_type(4))) float f32x4;

__device__ __forceinline__ float softplusf_(float x) {
    return (x > 20.f) ? x : log1pf(expf(x));
}
__device__ __forceinline__ short f2bf(float f) {
    union { float f; unsigned u; } v; v.f = f;
    unsigned r = v.u + 0x7FFFu + ((v.u >> 16) & 1u);   // RNE
    return (short)(r >> 16);
}
__device__ __forceinline__ unsigned pks(short a, short b) {
    return (unsigned)(unsigned short)a | ((unsigned)(unsigned short)b << 16);
}

// ---------------- fp32 -> bf16 conversion (x, Wq, Wk, Wv, Wo) ----------------
__global__ __launch_bounds__(256) void split_all(
    const float* __restrict__ x,  const float* __restrict__ Wq,
    const float* __restrict__ Wk, const float* __restrict__ Wv,
    const float* __restrict__ Wo,
    short* __restrict__ xh,  short* __restrict__ wqh,
    short* __restrict__ wkh, short* __restrict__ wvh, short* __restrict__ woh)
{
    int g = blockIdx.x * 256 + threadIdx.x;
    const float* src; short* dst; int base;
    if (g < 524288)       { src = x;  dst = xh;  base = g; }
    else if (g < 786432)  { src = Wq; dst = wqh; base = g - 524288; }
    else if (g < 1048576) { src = Wk; dst = wkh; base = g - 786432; }
    else if (g < 1310720) { src = Wv; dst = wvh; base = g - 1048576; }
    else                  { src = Wo; dst = woh; base = g - 1310720; }
    float4 v = *(const float4*)(src + (size_t)base * 4);
    uint2 hp; hp.x = pks(f2bf(v.x), f2bf(v.y)); hp.y = pks(f2bf(v.z), f2bf(v.w));
    *(uint2*)(dst + (size_t)base * 4) = hp;
}

// ------------- QKV GEMM (bf16 MFMA) with fused hyperbolic-map epilogue -------------
// C tile 128x128, BK=32, 4 waves x (32 rows x 128 cols). z: 0=Q, 1=K, 2=V.
// Tile cols span exactly 2 heads (h0 = bn/64, h0+1).
__global__ __launch_bounds__(256) void gemm_qkv(
    const short* __restrict__ Ap,
    const short* __restrict__ Wq, const short* __restrict__ Wk, const short* __restrict__ Wv,
    short* __restrict__ qh, short* __restrict__ kh, short* __restrict__ vtT,
    float* __restrict__ qnsT, float* __restrict__ knsT,
    const float* __restrict__ p_logc)
{
    const int z = blockIdx.z;
    const short* Bp = (z == 0) ? Wq : (z == 1 ? Wk : Wv);
    const int K = 1024;

    __shared__ short As[128 * 40];   // stride 40 shorts = 80B (16B-aligned, 2-way banks)
    __shared__ short Bs[128 * 40];

    const int tid = threadIdx.x;
    const int wv = tid >> 6, lane = tid & 63, quad = lane >> 4, l15 = lane & 15;
    const int bm = blockIdx.y * 128, bn = blockIdx.x * 128;
    const int r0 = tid >> 2, q4 = (tid & 3) * 8;

    f32x4 acc[2][8];
#pragma unroll
    for (int i = 0; i < 2; i++)
#pragma unroll
        for (int j = 0; j < 8; j++) acc[i][j] = (f32x4){0.f, 0.f, 0.f, 0.f};

    const size_t ar0 = (size_t)(bm + r0) * K, ar1 = (size_t)(bm + r0 + 64) * K;
    const size_t br0 = (size_t)(bn + r0) * K, br1 = (size_t)(bn + r0 + 64) * K;

    for (int k0 = 0; k0 < K; k0 += 32) {
        bf16x8 a0 = *(const bf16x8*)(Ap + ar0 + k0 + q4);
        bf16x8 a1 = *(const bf16x8*)(Ap + ar1 + k0 + q4);
        bf16x8 b0 = *(const bf16x8*)(Bp + br0 + k0 + q4);
        bf16x8 b1 = *(const bf16x8*)(Bp + br1 + k0 + q4);
        __syncthreads();
        *(bf16x8*)&As[r0 * 40 + q4]        = a0;
        *(bf16x8*)&As[(r0 + 64) * 40 + q4] = a1;
        *(bf16x8*)&Bs[r0 * 40 + q4]        = b0;
        *(bf16x8*)&Bs[(r0 + 64) * 40 + q4] = b1;
        __syncthreads();

        const int ab = (wv * 32 + l15) * 40 + quad * 8;
        bf16x8 fa0 = *(const bf16x8*)&As[ab];
        bf16x8 fa1 = *(const bf16x8*)&As[ab + 16 * 40];
#pragma unroll
        for (int nt = 0; nt < 8; nt++) {
            bf16x8 fb = *(const bf16x8*)&Bs[(nt * 16 + l15) * 40 + quad * 8];
            acc[0][nt] = __builtin_amdgcn_mfma_f32_16x16x32_bf16(fa0, fb, acc[0][nt], 0, 0, 0);
            acc[1][nt] = __builtin_amdgcn_mfma_f32_16x16x32_bf16(fa1, fb, acc[1][nt], 0, 0, 0);
        }
    }

    // ---- fused epilogue: exp_map (q,k: + norms) / exp_map∘log_map (v, transposed) ----
    const float c = softplusf_(p_logc[0]);
    const float sc = sqrtf(c);
    const int h0 = bn >> 6;
    const int mbase = bm + wv * 32;

    if (z < 2) {
        short* yout = (z == 0) ? qh : kh;
        float* nso  = (z == 0) ? qnsT : knsT;
#pragma unroll
        for (int mt = 0; mt < 2; mt++) {
            float fA[4], fB[4];
#pragma unroll
            for (int r = 0; r < 4; r++) {
                float s2A = 0.f, s2B = 0.f;
#pragma unroll
                for (int nt = 0; nt < 4; nt++) {
                    s2A += acc[mt][nt][r] * acc[mt][nt][r];
                    s2B += acc[mt][nt + 4][r] * acc[mt][nt + 4][r];
                }
#pragma unroll
                for (int mk = 1; mk < 16; mk <<= 1) {
                    s2A += __shfl_xor(s2A, mk, 64);
                    s2B += __shfl_xor(s2B, mk, 64);
                }
                float nA = fmaxf(sqrtf(s2A), EPS_), nB = fmaxf(sqrtf(s2B), EPS_);
                float facA = tanhf(sc * nA) / (sc * nA);
                float facB = tanhf(sc * nB) / (sc * nB);
                fA[r] = facA; fB[r] = facB;
                if (l15 == 0) {
                    int m = mbase + mt * 16 + quad * 4 + r;
                    int bI = m >> 10, s = m & 1023;
                    nso[(size_t)(bI * Hh + h0) * Ss + s]     = s2A * facA * facA;
                    nso[(size_t)(bI * Hh + h0 + 1) * Ss + s] = s2B * facB * facB;
                }
            }
#pragma unroll
            for (int nt = 0; nt < 8; nt++)
#pragma unroll
                for (int r = 0; r < 4; r++) {
                    int m = mbase + mt * 16 + quad * 4 + r;
                    float fac = (nt < 4) ? fA[r] : fB[r];
                    yout[(size_t)m * Dd + bn + nt * 16 + l15] = f2bf(acc[mt][nt][r] * fac);
                }
        }
    } else {
#pragma unroll
        for (int mt = 0; mt < 2; mt++) {
            float tA[4], tB[4];
#pragma unroll
            for (int r = 0; r < 4; r++) {
                float s2A = 0.f, s2B = 0.f;
#pragma unroll
                for (int nt = 0; nt < 4; nt++) {
                    s2A += acc[mt][nt][r] * acc[mt][nt][r];
                    s2B += acc[mt][nt + 4][r] * acc[mt][nt + 4][r];
                }
#pragma unroll
                for (int mk = 1; mk < 16; mk <<= 1) {
                    s2A += __shfl_xor(s2A, mk, 64);
                    s2B += __shfl_xor(s2B, mk, 64);
                }
                float nA = fmaxf(sqrtf(s2A), EPS_), nB = fmaxf(sqrtf(s2B), EPS_);
                float facA = tanhf(sc * nA) / (sc * nA);
                float facB = tanhf(sc * nB) / (sc * nB);
                float ynA = nA * facA, ynB = nB * facB;
                float yclA = fminf(ynA, 1.f / sc - EPS_);
                float yclB = fminf(ynB, 1.f / sc - EPS_);
                float f2A = atanhf(sc * yclA) / (sc * fmaxf(ynA, EPS_));
                float f2B = atanhf(sc * yclB) / (sc * fmaxf(ynB, EPS_));
                tA[r] = facA * f2A; tB[r] = facB * f2B;
            }
#pragma unroll
            for (int nt = 0; nt < 8; nt++) {
                int hh = h0 + (nt >> 2);
                int d  = (nt & 3) * 16 + l15;
                int m0 = mbase + mt * 16 + quad * 4;
                int bI = m0 >> 10, s0 = m0 & 1023;
                ushort4 pk4;
                pk4.x = (unsigned short)f2bf(acc[mt][nt][0] * ((nt < 4) ? tA[0] : tB[0]));
                pk4.y = (unsigned short)f2bf(acc[mt][nt][1] * ((nt < 4) ? tA[1] : tB[1]));
                pk4.z = (unsigned short)f2bf(acc[mt][nt][2] * ((nt < 4) ? tA[2] : tB[2]));
                pk4.w = (unsigned short)f2bf(acc[mt][nt][3] * ((nt < 4) ? tA[3] : tB[3]));
                *(ushort4*)&vtT[((size_t)(bI * Hh + hh) * DHh + d) * Ss + s0] = pk4;
            }
        }
    }
}

// ---------------- barrier-free MFMA flash attention ----------------
// 4 waves/block, wave handles 16 q rows. Fragments direct from global;
// P round-trips through wave-private LDS. Zero __syncthreads.
__global__ __launch_bounds__(256) void attn_mfma(
    const short* __restrict__ qh, const short* __restrict__ kh, const short* __restrict__ vtT,
    const float* __restrict__ qnsT, const float* __restrict__ knsT,
    short* __restrict__ ccb,
    const float* __restrict__ p_logc, const float* __restrict__ p_beta)
{
    const float c = softplusf_(p_logc[0]);
    const float sc = sqrtf(c);
    const float bp = softplusf_(p_beta[0]);
    const float kcoef = bp / sc;
    const float twoC = 2.f * c;

    const int h = blockIdx.y, b = blockIdx.z;
    const int wv = threadIdx.x >> 6, lane = threadIdx.x & 63;
    const int quad = lane >> 4, l15 = lane & 15;
    const int q0 = blockIdx.x * 64 + wv * 16;

    __shared__ short PsAll[4][16][72];
    short (*Ps)[72] = PsAll[wv];

    // Q A-fragments straight from global
    const short* qb = qh + (size_t)(b * Ss + q0 + l15) * Dd + h * DHh + quad * 8;
    bf16x8 qa0 = *(const bf16x8*)qb;
    bf16x8 qa1 = *(const bf16x8*)(qb + 32);

    float qn_r[4], irq[4];
    const float* qnp = qnsT + (size_t)(b * Hh + h) * Ss + q0 + quad * 4;
#pragma unroll
    for (int r = 0; r < 4; r++) { qn_r[r] = qnp[r]; irq[r] = 1.f / (1.f - c * qn_r[r]); }

    float lac[4] = {0.f, 0.f, 0.f, 0.f};
    f32x4 O4[4];
#pragma unroll
    for (int nt = 0; nt < 4; nt++) O4[nt] = (f32x4){0.f, 0.f, 0.f, 0.f};

    const float* knb = knsT + (size_t)(b * Hh + h) * Ss + l15;
    const short* kbase = kh  + (size_t)(b * Ss + l15) * Dd + h * DHh + quad * 8;
    const short* vbase = vtT + (size_t)((b * Hh + h) * DHh + l15) * Ss + quad * 8;

    for (int t0 = 0; t0 < Ss; t0 += 64) {
        // S = Q @ K^T (K B-frags direct from global)
        f32x4 acc[4];
#pragma unroll
        for (int nt = 0; nt < 4; nt++) {
            const short* kp = kbase + (size_t)(t0 + nt * 16) * Dd;
            bf16x8 b0 = *(const bf16x8*)kp;
            bf16x8 b1 = *(const bf16x8*)(kp + 32);
            f32x4 a = (f32x4){0.f, 0.f, 0.f, 0.f};
            a = __builtin_amdgcn_mfma_f32_16x16x32_bf16(qa0, b0, a, 0, 0, 0);
            a = __builtin_amdgcn_mfma_f32_16x16x32_bf16(qa1, b1, a, 0, 0, 0);
            acc[nt] = a;
        }
        float kn_c[4], ick[4];
#pragma unroll
        for (int nt = 0; nt < 4; nt++) {
            kn_c[nt] = knb[t0 + nt * 16];
            ick[nt] = 1.f / (1.f - c * kn_c[nt]);
        }
        // scores: p = u^(-bp/sc), u = arg + sqrt(arg^2-1); no max-tracking
        float s[4][4];
#pragma unroll
        for (int nt = 0; nt < 4; nt++) {
#pragma unroll
            for (int r = 0; r < 4; r++) {
                float dns = qn_r[r] + kn_c[nt] - 2.f * acc[nt][r];
                float invden = fminf(irq[r] * ick[nt], 1e5f);   // == 1/max(pr,EPS)
                float arg = fmaxf(fmaf(twoC * invden, dns, 1.f), 1.f + EPS_);
                float u = arg + sqrtf(fmaf(arg, arg, -1.f));
                float p = __expf(-kcoef * __logf(u));
                s[nt][r] = p;
                lac[r] += p;
            }
        }
        // P: C-layout -> A-layout via wave-private LDS (no barrier needed)
#pragma unroll
        for (int nt = 0; nt < 4; nt++)
#pragma unroll
            for (int r = 0; r < 4; r++)
                Ps[quad * 4 + r][nt * 16 + l15] = f2bf(s[nt][r]);
        bf16x8 pa0 = *(const bf16x8*)&Ps[l15][quad * 8];
        bf16x8 pa1 = *(const bf16x8*)&Ps[l15][32 + quad * 8];
        // O += P @ V (V B-frags direct from global, thanks to vtT layout)
#pragma unroll
        for (int nt = 0; nt < 4; nt++) {
            const short* vp = vbase + (size_t)(nt * 16) * Ss + t0;
            bf16x8 v0 = *(const bf16x8*)vp;
            bf16x8 v1 = *(const bf16x8*)(vp + 32);
            O4[nt] = __builtin_amdgcn_mfma_f32_16x16x32_bf16(pa0, v0, O4[nt], 0, 0, 0);
            O4[nt] = __builtin_amdgcn_mfma_f32_16x16x32_bf16(pa1, v1, O4[nt], 0, 0, 0);
        }
    }

    // normalize + exp_map + log_map, store bf16 concat
    float linv[4];
#pragma unroll
    for (int r = 0; r < 4; r++) {
        float ls = lac[r];
#pragma unroll
        for (int mk = 1; mk < 16; mk <<= 1) ls += __shfl_xor(ls, mk, 64);
        linv[r] = 1.f / ls;
    }
    float ot[4][4];
#pragma unroll
    for (int r = 0; r < 4; r++)
#pragma unroll
        for (int nt = 0; nt < 4; nt++) ot[nt][r] = O4[nt][r] * linv[r];
#pragma unroll
    for (int r = 0; r < 4; r++) {
        float t2 = 0.f;
#pragma unroll
        for (int nt = 0; nt < 4; nt++) t2 += ot[nt][r] * ot[nt][r];
#pragma unroll
        for (int mk = 1; mk < 16; mk <<= 1) t2 += __shfl_xor(t2, mk, 64);
        float n = fmaxf(sqrtf(t2), EPS_);
        float fac = tanhf(sc * n) / (sc * n);
        float y2 = t2 * fac * fac;
        float yn = fmaxf(sqrtf(y2), EPS_);
        float ycl = fminf(yn, 1.f / sc - EPS_);
        float fac2 = atanhf(sc * ycl) / (sc * yn);
        float tot = fac * fac2;
#pragma unroll
        for (int nt = 0; nt < 4; nt++) ot[nt][r] *= tot;
    }
#pragma unroll
    for (int nt = 0; nt < 4; nt++)
#pragma unroll
        for (int r = 0; r < 4; r++)
            ccb[(size_t)(b * Ss + q0 + quad * 4 + r) * Dd + h * DHh + nt * 16 + l15]
                = f2bf(ot[nt][r]);
}

// ---------------- output projection: out = ccb @ Wo^T (bf16 MFMA, fp32 out) ----------------
__global__ __launch_bounds__(256) void gemm_out(
    const short* __restrict__ Ap, const short* __restrict__ Bp,
    float* __restrict__ Cp)
{
    const int K = 1024, N = 1024;
    __shared__ short As[128 * 40];
    __shared__ short Bs[128 * 40];
    const int tid = threadIdx.x;
    const int wv = tid >> 6, lane = tid & 63, quad = lane >> 4, l15 = lane & 15;
    const int bm = blockIdx.y * 128, bn = blockIdx.x * 128;
    const int r0 = tid >> 2, q4 = (tid & 3) * 8;

    f32x4 acc[2][8];
#pragma unroll
    for (int i = 0; i < 2; i++)
#pragma unroll
        for (int j = 0; j < 8; j++) acc[i][j] = (f32x4){0.f, 0.f, 0.f, 0.f};

    const size_t ar0 = (size_t)(bm + r0) * K, ar1 = (size_t)(bm + r0 + 64) * K;
    const size_t br0 = (size_t)(bn + r0) * K, br1 = (size_t)(bn + r0 + 64) * K;

    for (int k0 = 0; k0 < K; k0 += 32) {
        bf16x8 a0 = *(const bf16x8*)(Ap + ar0 + k0 + q4);
        bf16x8 a1 = *(const bf16x8*)(Ap + ar1 + k0 + q4);
        bf16x8 b0 = *(const bf16x8*)(Bp + br0 + k0 + q4);
        bf16x8 b1 = *(const bf16x8*)(Bp + br1 + k0 + q4);
        __syncthreads();
        *(bf16x8*)&As[r0 * 40 + q4]        = a0;
        *(bf16x8*)&As[(r0 + 64) * 40 + q4] = a1;
        *(bf16x8*)&Bs[r0 * 40 + q4]        = b0;
        *(bf16x8*)&Bs[(r0 + 64) * 40 + q4] = b1;
        __syncthreads();

        const int ab = (wv * 32 + l15) * 40 + quad * 8;
        bf16x8 fa0 = *(const bf16x8*)&As[ab];
        bf16x8 fa1 = *(const bf16x8*)&As[ab + 16 * 40];
#pragma unroll
        for (int nt = 0; nt < 8; nt++) {
            bf16x8 fb = *(const bf16x8*)&Bs[(nt * 16 + l15) * 40 + quad * 8];
            acc[0][nt] = __builtin_amdgcn_mfma_f32_16x16x32_bf16(fa0, fb, acc[0][nt], 0, 0, 0);
            acc[1][nt] = __builtin_amdgcn_mfma_f32_16x16x32_bf16(fa1, fb, acc[1][nt], 0, 0, 0);
        }
    }
#pragma unroll
    for (int mt = 0; mt < 2; mt++)
#pragma unroll
        for (int nt = 0; nt < 8; nt++)
#pragma unroll
            for (int r = 0; r < 4; r++)
                Cp[(size_t)(bm + wv * 32 + mt * 16 + quad * 4 + r) * N + bn + nt * 16 + l15]
                    = acc[mt][nt][r];
}

extern "C" void kernel_launch(void* const* d_in, const int* in_sizes, int n_in,
                              void* d_out, int out_size, void* d_ws, size_t ws_size,
                              hipStream_t stream)
{
    const float* x    = (const float*)d_in[0];
    const float* Wq   = (const float*)d_in[1];
    const float* Wk   = (const float*)d_in[2];
    const float* Wv   = (const float*)d_in[3];
    const float* Wo   = (const float*)d_in[4];
    const float* logc = (const float*)d_in[5];
    const float* beta = (const float*)d_in[6];
    float* out = (float*)d_out;

    const size_t M2 = 2097152, M1 = 1048576;
    short* ws   = (short*)d_ws;
    short* xh   = ws;            // 2M shorts
    short* wqh  = xh + M2;       // 1M
    short* wkh  = wqh + M1;
    short* wvh  = wkh + M1;
    short* woh  = wvh + M1;
    short* qh   = woh + M1;      // 2M
    short* kh   = qh + M2;       // 2M
    short* vtT  = kh + M2;       // 2M
    short* ccb  = vtT + M2;      // 2M
    float* qnsT = (float*)(ccb + M2);   // 32K floats
    float* knsT = qnsT + 32768;         // 32K floats

    // 1) fp32 -> bf16 (x + 4 weights)
    split_all<<<dim3(6144), 256, 0, stream>>>(x, Wq, Wk, Wv, Wo, xh, wqh, wkh, wvh, woh);
    // 2) QKV projection + fused hyperbolic maps / norms
    gemm_qkv<<<dim3(8, 16, 3), 256, 0, stream>>>(xh, wqh, wkh, wvh,
        qh, kh, vtT, qnsT, knsT, logc);
    // 3) barrier-free flash attention -> bf16 concat
    attn_mfma<<<dim3(16, 16, 2), 256, 0, stream>>>(qh, kh, vtT, qnsT, knsT, ccb, logc, beta);
    // 4) output projection
    gemm_out<<<dim3(8, 16), 256, 0, stream>>>(ccb, woh, out);
}

// Round 5
// 263.441 us; speedup vs baseline: 3.0649x; 1.0090x over previous
//
#include <hip/hip_runtime.h>
#include <math.h>

// HyperbolicMultiHeadAttention — round 5:
//  * attention: S^T = K·Q^T so score regs feed PV (O^T = V^T·P^T) directly
//    via half-packed 16x16x32 B-frags — no LDS, no barriers, no transpose.
//    Split-K x2 (+fp32 partial combine) for occupancy; K-frag reg prefetch.
//  * GEMMs: m97-style global_load_lds(16B) staging, stride-32 LDS.
//  * gemm_qkv epilogue also stores 1/(1-c*kns) -> attn has zero divides/key.
// B=2, S=1024, D=1024, H=16, dh=64.

#define EPS_ 1e-5f

constexpr int Ss = 1024, Dd = 1024, Hh = 16, DHh = 64;

typedef __attribute__((ext_vector_type(8))) short bf16x8;
typedef __attribute__((ext_vector_type(4))) short s16x4;
typedef __attribute__((ext_vector_type(4))) float f32x4;

__device__ __forceinline__ float softplusf_(float x) {
    return (x > 20.f) ? x : log1pf(expf(x));
}
__device__ __forceinline__ float waveSum64(float v) {
#pragma unroll
    for (int m = 32; m >= 1; m >>= 1) v += __shfl_xor(v, m, 64);
    return v;
}
__device__ __forceinline__ short f2bf(float f) {
    union { float f; unsigned u; } v; v.f = f;
    unsigned r = v.u + 0x7FFFu + ((v.u >> 16) & 1u);   // RNE
    return (short)(r >> 16);
}
__device__ __forceinline__ unsigned pks(short a, short b) {
    return (unsigned)(unsigned short)a | ((unsigned)(unsigned short)b << 16);
}
// async global->LDS, 16B per lane; LDS dest = wave-uniform base + lane*16
__device__ __forceinline__ void gll16(const short* g, short* s) {
    __builtin_amdgcn_global_load_lds(
        (const __attribute__((address_space(1))) unsigned int*)g,
        (__attribute__((address_space(3))) unsigned int*)s, 16, 0, 0);
}

// ---------------- fp32 -> bf16 conversion (x, Wq, Wk, Wv, Wo) ----------------
__global__ __launch_bounds__(256) void split_all(
    const float* __restrict__ x,  const float* __restrict__ Wq,
    const float* __restrict__ Wk, const float* __restrict__ Wv,
    const float* __restrict__ Wo,
    short* __restrict__ xh,  short* __restrict__ wqh,
    short* __restrict__ wkh, short* __restrict__ wvh, short* __restrict__ woh)
{
    int g = blockIdx.x * 256 + threadIdx.x;
    const float* src; short* dst; int base;
    if (g < 524288)       { src = x;  dst = xh;  base = g; }
    else if (g < 786432)  { src = Wq; dst = wqh; base = g - 524288; }
    else if (g < 1048576) { src = Wk; dst = wkh; base = g - 786432; }
    else if (g < 1310720) { src = Wv; dst = wvh; base = g - 1048576; }
    else                  { src = Wo; dst = woh; base = g - 1310720; }
    float4 v = *(const float4*)(src + (size_t)base * 4);
    uint2 hp; hp.x = pks(f2bf(v.x), f2bf(v.y)); hp.y = pks(f2bf(v.z), f2bf(v.w));
    *(uint2*)(dst + (size_t)base * 4) = hp;
}

// ------------- QKV GEMM (bf16 MFMA, global_load_lds staging) + fused maps -------------
// C tile 128x128, BK=32, 4 waves x (32 rows x 128 cols). z: 0=Q, 1=K, 2=V.
__global__ __launch_bounds__(256) void gemm_qkv(
    const short* __restrict__ Ap,
    const short* __restrict__ Wq, const short* __restrict__ Wk, const short* __restrict__ Wv,
    short* __restrict__ qh, short* __restrict__ kh, short* __restrict__ vtT,
    float* __restrict__ qnsT, float* __restrict__ knsT, float* __restrict__ iknsT,
    const float* __restrict__ p_logc)
{
    const int z = blockIdx.z;
    const short* Bp = (z == 0) ? Wq : (z == 1 ? Wk : Wv);
    const int K = 1024;

    __shared__ short As[4096];   // 128 rows x 32 k (stride 32 shorts, 64B rows)
    __shared__ short Bs[4096];

    const int tid = threadIdx.x;
    const int wv = tid >> 6, lane = tid & 63, quad = lane >> 4, l15 = lane & 15;
    const int bm = blockIdx.y * 128, bn = blockIdx.x * 128;
    const int lr = lane >> 2, lc = (lane & 3) * 8;   // staging coords within wave

    const short* ga0 = Ap + (size_t)(bm + wv * 16 + lr) * K + lc;
    const short* ga1 = ga0 + (size_t)64 * K;
    const short* gb0 = Bp + (size_t)(bn + wv * 16 + lr) * K + lc;
    const short* gb1 = gb0 + (size_t)64 * K;
    short* lA0 = As + wv * 512;          // wave-uniform LDS bases
    short* lA1 = As + 2048 + wv * 512;
    short* lB0 = Bs + wv * 512;
    short* lB1 = Bs + 2048 + wv * 512;

    f32x4 acc[2][8];
#pragma unroll
    for (int i = 0; i < 2; i++)
#pragma unroll
        for (int j = 0; j < 8; j++) acc[i][j] = (f32x4){0.f, 0.f, 0.f, 0.f};

    for (int k0 = 0; k0 < K; k0 += 32) {
        __syncthreads();
        gll16(ga0 + k0, lA0);
        gll16(ga1 + k0, lA1);
        gll16(gb0 + k0, lB0);
        gll16(gb1 + k0, lB1);
        __syncthreads();   // compiler drains vmcnt before barrier

        const int ab = (wv * 32 + l15) * 32 + quad * 8;
        bf16x8 fa0 = *(const bf16x8*)&As[ab];
        bf16x8 fa1 = *(const bf16x8*)&As[ab + 16 * 32];
#pragma unroll
        for (int nt = 0; nt < 8; nt++) {
            bf16x8 fb = *(const bf16x8*)&Bs[(nt * 16 + l15) * 32 + quad * 8];
            acc[0][nt] = __builtin_amdgcn_mfma_f32_16x16x32_bf16(fa0, fb, acc[0][nt], 0, 0, 0);
            acc[1][nt] = __builtin_amdgcn_mfma_f32_16x16x32_bf16(fa1, fb, acc[1][nt], 0, 0, 0);
        }
    }

    // ---- fused epilogue ----
    const float c = softplusf_(p_logc[0]);
    const float sc = sqrtf(c);
    const int h0 = bn >> 6;
    const int mbase = bm + wv * 32;

    if (z < 2) {
        short* yout = (z == 0) ? qh : kh;
        float* nso  = (z == 0) ? qnsT : knsT;
#pragma unroll
        for (int mt = 0; mt < 2; mt++) {
            float fA[4], fB[4];
#pragma unroll
            for (int r = 0; r < 4; r++) {
                float s2A = 0.f, s2B = 0.f;
#pragma unroll
                for (int nt = 0; nt < 4; nt++) {
                    s2A += acc[mt][nt][r] * acc[mt][nt][r];
                    s2B += acc[mt][nt + 4][r] * acc[mt][nt + 4][r];
                }
#pragma unroll
                for (int mk = 1; mk < 16; mk <<= 1) {
                    s2A += __shfl_xor(s2A, mk, 64);
                    s2B += __shfl_xor(s2B, mk, 64);
                }
                float nA = fmaxf(sqrtf(s2A), EPS_), nB = fmaxf(sqrtf(s2B), EPS_);
                float facA = tanhf(sc * nA) / (sc * nA);
                float facB = tanhf(sc * nB) / (sc * nB);
                fA[r] = facA; fB[r] = facB;
                if (l15 == 0) {
                    int m = mbase + mt * 16 + quad * 4 + r;
                    int bI = m >> 10, s = m & 1023;
                    float ynsA = s2A * facA * facA;
                    float ynsB = s2B * facB * facB;
                    nso[(size_t)(bI * Hh + h0) * Ss + s]     = ynsA;
                    nso[(size_t)(bI * Hh + h0 + 1) * Ss + s] = ynsB;
                    if (z == 1) {
                        iknsT[(size_t)(bI * Hh + h0) * Ss + s]     = 1.f / (1.f - c * ynsA);
                        iknsT[(size_t)(bI * Hh + h0 + 1) * Ss + s] = 1.f / (1.f - c * ynsB);
                    }
                }
            }
#pragma unroll
            for (int nt = 0; nt < 8; nt++)
#pragma unroll
                for (int r = 0; r < 4; r++) {
                    int m = mbase + mt * 16 + quad * 4 + r;
                    float fac = (nt < 4) ? fA[r] : fB[r];
                    yout[(size_t)m * Dd + bn + nt * 16 + l15] = f2bf(acc[mt][nt][r] * fac);
                }
        }
    } else {
#pragma unroll
        for (int mt = 0; mt < 2; mt++) {
            float tA[4], tB[4];
#pragma unroll
            for (int r = 0; r < 4; r++) {
                float s2A = 0.f, s2B = 0.f;
#pragma unroll
                for (int nt = 0; nt < 4; nt++) {
                    s2A += acc[mt][nt][r] * acc[mt][nt][r];
                    s2B += acc[mt][nt + 4][r] * acc[mt][nt + 4][r];
                }
#pragma unroll
                for (int mk = 1; mk < 16; mk <<= 1) {
                    s2A += __shfl_xor(s2A, mk, 64);
                    s2B += __shfl_xor(s2B, mk, 64);
                }
                float nA = fmaxf(sqrtf(s2A), EPS_), nB = fmaxf(sqrtf(s2B), EPS_);
                float facA = tanhf(sc * nA) / (sc * nA);
                float facB = tanhf(sc * nB) / (sc * nB);
                float ynA = nA * facA, ynB = nB * facB;
                float yclA = fminf(ynA, 1.f / sc - EPS_);
                float yclB = fminf(ynB, 1.f / sc - EPS_);
                float f2A = atanhf(sc * yclA) / (sc * fmaxf(ynA, EPS_));
                float f2B = atanhf(sc * yclB) / (sc * fmaxf(ynB, EPS_));
                tA[r] = facA * f2A; tB[r] = facB * f2B;
            }
#pragma unroll
            for (int nt = 0; nt < 8; nt++) {
                int hh = h0 + (nt >> 2);
                int d  = (nt & 3) * 16 + l15;
                int m0 = mbase + mt * 16 + quad * 4;
                int bI = m0 >> 10, s0 = m0 & 1023;
                ushort4 pk4;
                pk4.x = (unsigned short)f2bf(acc[mt][nt][0] * ((nt < 4) ? tA[0] : tB[0]));
                pk4.y = (unsigned short)f2bf(acc[mt][nt][1] * ((nt < 4) ? tA[1] : tB[1]));
                pk4.z = (unsigned short)f2bf(acc[mt][nt][2] * ((nt < 4) ? tA[2] : tB[2]));
                pk4.w = (unsigned short)f2bf(acc[mt][nt][3] * ((nt < 4) ? tA[3] : tB[3]));
                *(ushort4*)&vtT[((size_t)(bI * Hh + hh) * DHh + d) * Ss + s0] = pk4;
            }
        }
    }
}

// ---------------- LDS-free MFMA flash attention (split-K x2, partials out) ----------------
// Wave = 16 q rows, block = 4 waves (64-q tile). grid.x = 16 qtiles x 2 kranges.
// S^T = K·Q^T -> lane holds (t = nt*16+quad*4+r, q = l15); scores convert
// in-register to PV B-frags (half-packed 16x16x32). O^T accumulates in C-layout.
__global__ __launch_bounds__(256) void attn_mfma(
    const short* __restrict__ qh, const short* __restrict__ kh, const short* __restrict__ vtT,
    const float* __restrict__ qnsT, const float* __restrict__ knsT, const float* __restrict__ iknsT,
    float* __restrict__ Opart, float* __restrict__ lpart,
    const float* __restrict__ p_logc, const float* __restrict__ p_beta)
{
    const float c = softplusf_(p_logc[0]);
    const float sc = sqrtf(c);
    const float bp = softplusf_(p_beta[0]);
    const float kcoef = bp / sc;
    const float twoC = 2.f * c;

    const int h = blockIdx.y, b = blockIdx.z;
    const int kr = blockIdx.x & 1, qt = blockIdx.x >> 1;
    const int wv = threadIdx.x >> 6, lane = threadIdx.x & 63;
    const int quad = lane >> 4, l15 = lane & 15;
    const int bh = b * Hh + h;
    const int q = qt * 64 + wv * 16 + l15;

    // Q B-fragments (n = q = l15, k-slots = d)
    const short* qb = qh + (size_t)(b * Ss + q) * Dd + h * DHh + quad * 8;
    bf16x8 qf0 = *(const bf16x8*)qb;
    bf16x8 qf1 = *(const bf16x8*)(qb + 32);

    const float qn = qnsT[(size_t)bh * Ss + q];
    const float irq = 1.f / (1.f - c * qn);

    f32x4 O4[4];
#pragma unroll
    for (int nt = 0; nt < 4; nt++) O4[nt] = (f32x4){0.f, 0.f, 0.f, 0.f};
    float lac = 0.f;

    const int tbase = kr * 512;
    const short* kb  = kh + (size_t)b * Ss * Dd + h * DHh + quad * 8;
    const short* vb  = vtT + ((size_t)bh * DHh + l15) * Ss;
    const float* knb  = knsT + (size_t)bh * Ss;
    const float* iknb = iknsT + (size_t)bh * Ss;

    // preload first chunk K A-fragments (m = t rows)
    bf16x8 kf0[4], kf1[4];
#pragma unroll
    for (int nt = 0; nt < 4; nt++) {
        const short* kp = kb + (size_t)(tbase + nt * 16 + l15) * Dd;
        kf0[nt] = *(const bf16x8*)kp;
        kf1[nt] = *(const bf16x8*)(kp + 32);
    }

#pragma unroll
    for (int ch = 0; ch < 8; ch++) {
        const int t0 = tbase + ch * 64;

        // V A-fragments (half-pair packing, t(k') map) + key norms — issue early
        bf16x8 vf[4][2];
        f32x4 kn4[4], ik4[4];
#pragma unroll
        for (int nt = 0; nt < 4; nt++) {
            const short* vr = vb + (size_t)(nt * 16) * Ss + t0 + quad * 4;
            s16x4 a0 = *(const s16x4*)(vr);          // t0 + quad*4
            s16x4 a1 = *(const s16x4*)(vr + 16);     // t0 + 16 + quad*4
            s16x4 a2 = *(const s16x4*)(vr + 32);     // t0 + 32 + quad*4
            s16x4 a3 = *(const s16x4*)(vr + 48);     // t0 + 48 + quad*4
            vf[nt][0] = __builtin_shufflevector(a0, a1, 0, 1, 2, 3, 4, 5, 6, 7);
            vf[nt][1] = __builtin_shufflevector(a2, a3, 0, 1, 2, 3, 4, 5, 6, 7);
            kn4[nt] = *(const f32x4*)(knb  + t0 + nt * 16 + quad * 4);
            ik4[nt] = *(const f32x4*)(iknb + t0 + nt * 16 + quad * 4);
        }

        // S^T = K·Q^T
        f32x4 acc[4];
#pragma unroll
        for (int nt = 0; nt < 4; nt++) {
            f32x4 a = (f32x4){0.f, 0.f, 0.f, 0.f};
            a = __builtin_amdgcn_mfma_f32_16x16x32_bf16(kf0[nt], qf0, a, 0, 0, 0);
            a = __builtin_amdgcn_mfma_f32_16x16x32_bf16(kf1[nt], qf1, a, 0, 0, 0);
            acc[nt] = a;
        }

        // prefetch next chunk K frags during score math
        if (ch < 7) {
#pragma unroll
            for (int nt = 0; nt < 4; nt++) {
                const short* kp = kb + (size_t)(t0 + 64 + nt * 16 + l15) * Dd;
                kf0[nt] = *(const bf16x8*)kp;
                kf1[nt] = *(const bf16x8*)(kp + 32);
            }
        }

        // scores: p = u^(-bp/sc), u = arg + sqrt(arg^2-1)
        float sv[4][4];
#pragma unroll
        for (int nt = 0; nt < 4; nt++) {
#pragma unroll
            for (int r = 0; r < 4; r++) {
                float kn = kn4[nt][r];
                float dns = qn + kn - 2.f * acc[nt][r];
                float ivd = fminf(irq * ik4[nt][r], 1e5f);   // 1/max(den, EPS)
                float arg = fmaxf(fmaf(twoC * ivd, dns, 1.f), 1.f + EPS_);
                float u = arg + sqrtf(fmaf(arg, arg, -1.f));
                float p = __expf(-kcoef * __logf(u));
                sv[nt][r] = p;
                lac += p;
            }
        }

        // in-register P^T B-frags: pb0 covers t0..t0+31, pb1 t0+32..t0+63
        bf16x8 pb0, pb1;
#pragma unroll
        for (int j = 0; j < 4; j++) {
            pb0[j]     = f2bf(sv[0][j]);
            pb0[j + 4] = f2bf(sv[1][j]);
            pb1[j]     = f2bf(sv[2][j]);
            pb1[j + 4] = f2bf(sv[3][j]);
        }

        // O^T += V^T · P^T
#pragma unroll
        for (int nt = 0; nt < 4; nt++) {
            O4[nt] = __builtin_amdgcn_mfma_f32_16x16x32_bf16(vf[nt][0], pb0, O4[nt], 0, 0, 0);
            O4[nt] = __builtin_amdgcn_mfma_f32_16x16x32_bf16(vf[nt][1], pb1, O4[nt], 0, 0, 0);
        }
    }

    // reduce l across quads; store partials
    lac += __shfl_xor(lac, 16, 64);
    lac += __shfl_xor(lac, 32, 64);
    float* ob = Opart + (((size_t)bh * 2 + kr) * Ss + q) * DHh;
#pragma unroll
    for (int nt = 0; nt < 4; nt++)
        *(f32x4*)(ob + nt * 16 + quad * 4) = O4[nt];
    if (lane < 16)
        lpart[((size_t)bh * 2 + kr) * Ss + qt * 64 + wv * 16 + lane] = lac;
}

// ---------------- combine split-K partials + exp/log-map epilogue ----------------
__global__ __launch_bounds__(256) void attn_combine(
    const float* __restrict__ Opart, const float* __restrict__ lpart,
    short* __restrict__ ccb, const float* __restrict__ p_logc)
{
    const float c = softplusf_(p_logc[0]);
    const float sc = sqrtf(c);
    const int wv = threadIdx.x >> 6, d = threadIdx.x & 63;
    const int task = blockIdx.x * 4 + wv;        // bh*1024 + s
    const int bh = task >> 10, s = task & 1023;

    const float* o0 = Opart + (((size_t)bh * 2 + 0) * Ss + s) * DHh + d;
    const float* o1 = Opart + (((size_t)bh * 2 + 1) * Ss + s) * DHh + d;
    float O = *o0 + *o1;
    float l = lpart[((size_t)bh * 2) * Ss + s] + lpart[((size_t)bh * 2 + 1) * Ss + s];
    float ot = O / l;

    float t2 = waveSum64(ot * ot);
    float n = fmaxf(sqrtf(t2), EPS_);
    float fac = tanhf(sc * n) / (sc * n);          // exp_map
    float y2 = t2 * fac * fac;
    float yn = fmaxf(sqrtf(y2), EPS_);
    float ycl = fminf(yn, 1.f / sc - EPS_);
    float fac2 = atanhf(sc * ycl) / (sc * yn);     // log_map
    float tot = fac * fac2;

    int b = bh >> 4, hh = bh & 15;
    ccb[(size_t)(b * Ss + s) * Dd + hh * DHh + d] = f2bf(ot * tot);
}

// ---------------- output projection: out = ccb @ Wo^T ----------------
__global__ __launch_bounds__(256) void gemm_out(
    const short* __restrict__ Ap, const short* __restrict__ Bp,
    float* __restrict__ Cp)
{
    const int K = 1024, N = 1024;
    __shared__ short As[4096];
    __shared__ short Bs[4096];
    const int tid = threadIdx.x;
    const int wv = tid >> 6, lane = tid & 63, quad = lane >> 4, l15 = lane & 15;
    const int bm = blockIdx.y * 128, bn = blockIdx.x * 128;
    const int lr = lane >> 2, lc = (lane & 3) * 8;

    const short* ga0 = Ap + (size_t)(bm + wv * 16 + lr) * K + lc;
    const short* ga1 = ga0 + (size_t)64 * K;
    const short* gb0 = Bp + (size_t)(bn + wv * 16 + lr) * K + lc;
    const short* gb1 = gb0 + (size_t)64 * K;
    short* lA0 = As + wv * 512;
    short* lA1 = As + 2048 + wv * 512;
    short* lB0 = Bs + wv * 512;
    short* lB1 = Bs + 2048 + wv * 512;

    f32x4 acc[2][8];
#pragma unroll
    for (int i = 0; i < 2; i++)
#pragma unroll
        for (int j = 0; j < 8; j++) acc[i][j] = (f32x4){0.f, 0.f, 0.f, 0.f};

    for (int k0 = 0; k0 < K; k0 += 32) {
        __syncthreads();
        gll16(ga0 + k0, lA0);
        gll16(ga1 + k0, lA1);
        gll16(gb0 + k0, lB0);
        gll16(gb1 + k0, lB1);
        __syncthreads();

        const int ab = (wv * 32 + l15) * 32 + quad * 8;
        bf16x8 fa0 = *(const bf16x8*)&As[ab];
        bf16x8 fa1 = *(const bf16x8*)&As[ab + 16 * 32];
#pragma unroll
        for (int nt = 0; nt < 8; nt++) {
            bf16x8 fb = *(const bf16x8*)&Bs[(nt * 16 + l15) * 32 + quad * 8];
            acc[0][nt] = __builtin_amdgcn_mfma_f32_16x16x32_bf16(fa0, fb, acc[0][nt], 0, 0, 0);
            acc[1][nt] = __builtin_amdgcn_mfma_f32_16x16x32_bf16(fa1, fb, acc[1][nt], 0, 0, 0);
        }
    }
#pragma unroll
    for (int mt = 0; mt < 2; mt++)
#pragma unroll
        for (int nt = 0; nt < 8; nt++)
#pragma unroll
            for (int r = 0; r < 4; r++)
                Cp[(size_t)(bm + wv * 32 + mt * 16 + quad * 4 + r) * N + bn + nt * 16 + l15]
                    = acc[mt][nt][r];
}

extern "C" void kernel_launch(void* const* d_in, const int* in_sizes, int n_in,
                              void* d_out, int out_size, void* d_ws, size_t ws_size,
                              hipStream_t stream)
{
    const float* x    = (const float*)d_in[0];
    const float* Wq   = (const float*)d_in[1];
    const float* Wk   = (const float*)d_in[2];
    const float* Wv   = (const float*)d_in[3];
    const float* Wo   = (const float*)d_in[4];
    const float* logc = (const float*)d_in[5];
    const float* beta = (const float*)d_in[6];
    float* out = (float*)d_out;

    const size_t M2 = 2097152, M1 = 1048576;
    short* ws    = (short*)d_ws;
    short* xh    = ws;                 // 2M shorts
    short* wqh   = xh + M2;            // 1M each
    short* wkh   = wqh + M1;
    short* wvh   = wkh + M1;
    short* woh   = wvh + M1;
    short* qh    = woh + M1;           // 2M each
    short* kh    = qh + M2;
    short* vtT   = kh + M2;
    short* ccb   = vtT + M2;
    float* qnsT  = (float*)(ccb + M2); // 32K floats each
    float* knsT  = qnsT + 32768;
    float* iknsT = knsT + 32768;
    float* Opart = iknsT + 32768;      // 4M floats (16MB)
    float* lpart = Opart + 4194304;    // 64K floats

    // 1) fp32 -> bf16
    split_all<<<dim3(6144), 256, 0, stream>>>(x, Wq, Wk, Wv, Wo, xh, wqh, wkh, wvh, woh);
    // 2) QKV projection + fused hyperbolic maps / norms / inverse-denoms
    gemm_qkv<<<dim3(8, 16, 3), 256, 0, stream>>>(xh, wqh, wkh, wvh,
        qh, kh, vtT, qnsT, knsT, iknsT, logc);
    // 3) LDS-free flash attention, split-K x2 -> fp32 partials
    attn_mfma<<<dim3(32, 16, 2), 256, 0, stream>>>(qh, kh, vtT, qnsT, knsT, iknsT,
        Opart, lpart, logc, beta);
    // 4) combine partials + exp/log maps -> bf16 concat
    attn_combine<<<dim3(8192), 256, 0, stream>>>(Opart, lpart, ccb, logc);
    // 5) output projection
    gemm_out<<<dim3(8, 16), 256, 0, stream>>>(ccb, woh, out);
}